// Round 1
// baseline (763.545 us; speedup 1.0000x reference)
//
#include <hip/hip_runtime.h>
#include <math.h>

#define B_ 4
#define C_ 2048
#define E_ 1024
#define H_ 16
#define D_ 64
#define ROWS_ (B_*C_)   // 8192

typedef __bf16 bf16x8 __attribute__((ext_vector_type(8)));
typedef float f32x4 __attribute__((ext_vector_type(4)));

__device__ __forceinline__ float b2f(unsigned short u) {
  unsigned int x = ((unsigned int)u) << 16;
  return __builtin_bit_cast(float, x);
}
__device__ __forceinline__ unsigned short f2b(float f) {
  unsigned int x = __builtin_bit_cast(unsigned int, f);
  unsigned int r = (x + 0x7FFFu + ((x >> 16) & 1u)) >> 16;
  return (unsigned short)r;
}
__device__ __forceinline__ unsigned short tob(float f) { return f2b(f); }
__device__ __forceinline__ unsigned short tob(unsigned short u) { return u; }
__device__ __forceinline__ void store_out(float* p, float v) { *p = v; }
__device__ __forceinline__ void store_out(unsigned short* p, float v) { *p = f2b(v); }

__device__ __forceinline__ void async16(const void* g, void* l) {
  __builtin_amdgcn_global_load_lds(
      (__attribute__((address_space(1))) unsigned int*)g,
      (__attribute__((address_space(3))) unsigned int*)l, 16, 0, 0);
}

// ------------- 64x64 tiled transpose, InT -> bf16 ----------------------
template <typename InT>
__global__ __launch_bounds__(256) void transpose64(
    const InT* __restrict__ in, unsigned short* __restrict__ out,
    int s_in, int s_out, int Hz, long zs_b, long zs_h, long zs_out)
{
  __shared__ unsigned short t[64][65];
  int z = blockIdx.z;
  long ib = (long)(z / Hz) * zs_b + (long)(z % Hz) * zs_h;
  long ob = (long)z * zs_out;
  int r0 = blockIdx.y * 64, c0 = blockIdx.x * 64;
  int lane = threadIdx.x & 63, grp = threadIdx.x >> 6;
  for (int i = grp; i < 64; i += 4)
    t[i][lane] = tob(in[ib + (long)(r0 + i) * s_in + c0 + lane]);
  __syncthreads();
  for (int i = grp; i < 64; i += 4)
    out[ob + (long)(c0 + i) * s_out + r0 + lane] = t[lane][i];
}

__global__ void concat_bias(const float* __restrict__ q,
                            const float* __restrict__ k,
                            const float* __restrict__ v,
                            float* __restrict__ o)
{
  int i = blockIdx.x * 256 + threadIdx.x;  // 3072 total
  o[i] = (i < 1024) ? q[i] : (i < 2048) ? k[i - 1024] : v[i - 2048];
}

// ---------------- LayerNorm (optionally fused residual add) ------------
__global__ __launch_bounds__(256) void ln_kernel(
    const float* __restrict__ xin, const unsigned short* __restrict__ addend,
    const float* __restrict__ g, const float* __restrict__ beta,
    unsigned short* __restrict__ yout, float* __restrict__ out1)
{
  int row = blockIdx.x, tid = threadIdx.x;
  size_t base = (size_t)row * E_ + tid * 4;
  float4 xa = *(const float4*)(xin + base);
  float v0 = xa.x, v1 = xa.y, v2 = xa.z, v3 = xa.w;
  if (addend) {
    ushort4 aa = *(const ushort4*)(addend + base);
    v0 += b2f(aa.x); v1 += b2f(aa.y); v2 += b2f(aa.z); v3 += b2f(aa.w);
  }
  if (out1) {
    *(float4*)(out1 + base) = make_float4(v0, v1, v2, v3);
  }
  float s = v0 + v1 + v2 + v3;
  float sq = v0*v0 + v1*v1 + v2*v2 + v3*v3;
  #pragma unroll
  for (int off = 32; off >= 1; off >>= 1) {
    s  += __shfl_xor(s, off);
    sq += __shfl_xor(sq, off);
  }
  __shared__ float red[8];
  int wid = tid >> 6;
  if ((tid & 63) == 0) { red[wid] = s; red[4 + wid] = sq; }
  __syncthreads();
  s  = red[0] + red[1] + red[2] + red[3];
  sq = red[4] + red[5] + red[6] + red[7];
  float mu = s * (1.0f / E_);
  float var = sq * (1.0f / E_) - mu * mu;
  float rs = rsqrtf(var + 1e-5f);
  float4 ga = *(const float4*)(g + tid * 4);
  float4 ba = *(const float4*)(beta + tid * 4);
  ushort4 o;
  o.x = f2b((v0 - mu) * rs * ga.x + ba.x);
  o.y = f2b((v1 - mu) * rs * ga.y + ba.y);
  o.z = f2b((v2 - mu) * rs * ga.z + ba.z);
  o.w = f2b((v3 - mu) * rs * ga.w + ba.w);
  *(ushort4*)(yout + base) = o;
}

// ===================== 256x256 8-phase bf16 GEMM =======================
// C = A @ Bt^T (+bias)(+relu)(+resid on z==0).  BM=BN=256, BK=64,
// 8 waves (2M x 4N), per-wave 128x64 output (acc[8][4] f32x4).
// Double-buffered LDS (128 KiB): buf[t&1] holds K-tile t (A 256x64 +
// B 256x64).  Per iteration = 2 K-tiles = 8 phases; each phase:
//   {ds_read subtile || issue one 128x64 half-tile stage} -> barrier ->
//   lgkmcnt(0) -> setprio(1) 16 MFMA setprio(0) -> [vmcnt(4) @p4/p8] ->
//   barrier.
// Counted vmcnt(4) sits BEFORE the barrier that precedes the reads it
// protects (cross-wave visibility).  Steady-state in-flight: 12 loads
// peak, 4 after each wait.  Stage of any LDS region is issued >=1
// barrier after that region's last read completes (WAR-safe).
// XOR swizzle: pre-swizzled global source column + linear LDS dest +
// swizzled ds_read (verified conflict-free: SQ_LDS_BANK_CONFLICT=0).
// Grid decode assumes M=8192 (32 M-blocks), XCD-chunked: each XCD owns
// 4 contiguous bm strips, bn-major sweep.
#define BARC() { asm volatile("" ::: "memory"); __builtin_amdgcn_s_barrier(); asm volatile("" ::: "memory"); }

#define MFMA_Q(mh, Af, Bf) do {                                             \
  __builtin_amdgcn_s_setprio(1);                                            \
  _Pragma("unroll")                                                         \
  for (int mt_ = 0; mt_ < 4; ++mt_)                                         \
    _Pragma("unroll")                                                       \
    for (int nt_ = 0; nt_ < 4; ++nt_)                                       \
      acc[(mh)*4+mt_][nt_] = __builtin_amdgcn_mfma_f32_16x16x32_bf16(       \
          Af[(mh)*4+mt_], Bf[nt_], acc[(mh)*4+mt_][nt_], 0, 0, 0);          \
  __builtin_amdgcn_s_setprio(0);                                            \
} while (0)

template <typename OutT>
__global__ __launch_bounds__(512, 2) void gemm256(
    const unsigned short* __restrict__ A, const unsigned short* __restrict__ Bt,
    const float* __restrict__ bias, const float* __restrict__ resid,
    OutT* __restrict__ Co, int M, int N, int K, int lda, int ldb,
    int relu, size_t zs)
{
  __shared__ __align__(16) unsigned short As[2][256 * 64];
  __shared__ __align__(16) unsigned short Bs[2][256 * 64];
  int tid = threadIdx.x, lane = tid & 63, wid = tid >> 6;
  int lane15 = lane & 15, quad = lane >> 4;
  int wm = wid >> 2, wn = wid & 3;

  // XCD-chunked block swizzle (M/256 == 32 assumed)
  int i = blockIdx.x;
  int xcd = i & 7, c = i >> 3;
  int bm = xcd * 4 + (c & 3);
  int bn = c >> 2;
  size_t koff = (size_t)blockIdx.z * K;
  int z0 = (blockIdx.z == 0);
  Co += (size_t)blockIdx.z * zs;

  // staging: thread -> (row sr 0..63, colblock sc 0..7), 2 rounds of 64 rows
  int sr = tid >> 3, sc = tid & 7;
  int scs = (sc ^ (sr & 7)) * 8;                 // pre-swizzled global col
  const unsigned short* Ag = A + koff + (size_t)(bm * 256 + sr) * lda + scs;
  const unsigned short* Bg = Bt + koff + (size_t)(bn * 256 + sr) * ldb + scs;
  int dstb = wid * 512;                          // wave-uniform LDS base (ushorts)

  int NT = K >> 6;                               // 64-wide K tiles (even)

  f32x4 acc[8][4];
  #pragma unroll
  for (int m = 0; m < 8; ++m)
    #pragma unroll
    for (int n = 0; n < 4; ++n) acc[m][n] = 0.0f;

  auto stA = [&](int kt, int h) {
    const unsigned short* s = Ag + (size_t)(h * 128) * lda + kt * 64;
    unsigned short* d = &As[kt & 1][h * 8192 + dstb];
    async16(s, d);
    async16(s + (size_t)64 * lda, d + 4096);
  };
  auto stB = [&](int kt, int h) {
    const unsigned short* s = Bg + (size_t)(h * 128) * ldb + kt * 64;
    unsigned short* d = &Bs[kt & 1][h * 8192 + dstb];
    async16(s, d);
    async16(s + (size_t)64 * ldb, d + 4096);
  };
  int rsw = lane15 & 7;
  auto ldA = [&](int buf, int m, int kk) {
    int row = wm * 128 + m * 16 + lane15;
    return *(const bf16x8*)&As[buf][row * 64 + (((kk * 4 + quad) ^ rsw) * 8)];
  };
  auto ldB = [&](int buf, int n, int kk) {
    int row = wn * 64 + n * 16 + lane15;
    return *(const bf16x8*)&Bs[buf][row * 64 + (((kk * 4 + quad) ^ rsw) * 8)];
  };

  // prologue: tile0 complete + tile1 A-halves; wait so tile0 landed.
  stA(0, 0); stA(0, 1); stB(0, 0); stB(0, 1);
  stA(1, 0); stA(1, 1);
  asm volatile("s_waitcnt vmcnt(4)" ::: "memory");
  __builtin_amdgcn_s_barrier();

  for (int it = 0; it < (NT >> 1); ++it) {
    int u = 2 * it;
    bool more = (u + 2 < NT);
    bf16x8 a0[8], b0[4], a1[8], b1[4];

    // ---- p1: read buf0 kk=0; stage (u+1)B0 -> Bs[1].h0 ----
    #pragma unroll
    for (int m = 0; m < 8; ++m) a0[m] = ldA(0, m, 0);
    #pragma unroll
    for (int n = 0; n < 4; ++n) b0[n] = ldB(0, n, 0);
    stB(u + 1, 0);
    BARC();
    asm volatile("s_waitcnt lgkmcnt(0)" ::: "memory");
    MFMA_Q(0, a0, b0);
    BARC();
    // ---- p2: read buf0 kk=1; stage (u+1)B1 ----
    #pragma unroll
    for (int m = 0; m < 8; ++m) a1[m] = ldA(0, m, 1);
    #pragma unroll
    for (int n = 0; n < 4; ++n) b1[n] = ldB(0, n, 1);
    stB(u + 1, 1);
    BARC();
    asm volatile("s_waitcnt lgkmcnt(0)" ::: "memory");
    MFMA_Q(1, a0, b0);
    BARC();
    // ---- p3: stage (u+2)A0 -> As[0].h0 (buf0 A reads done @p2) ----
    if (more) stA(u + 2, 0);
    BARC();
    MFMA_Q(0, a1, b1);
    BARC();
    // ---- p4: stage (u+2)A1; wait so tile u+1 landed before p5 reads ----
    if (more) stA(u + 2, 1);
    BARC();
    MFMA_Q(1, a1, b1);
    if (more) { asm volatile("s_waitcnt vmcnt(4)" ::: "memory"); }
    else      { asm volatile("s_waitcnt vmcnt(0)" ::: "memory"); }
    BARC();
    // ---- p5: read buf1 kk=0; stage (u+2)B0 -> Bs[0].h0 ----
    #pragma unroll
    for (int m = 0; m < 8; ++m) a0[m] = ldA(1, m, 0);
    #pragma unroll
    for (int n = 0; n < 4; ++n) b0[n] = ldB(1, n, 0);
    if (more) stB(u + 2, 0);
    BARC();
    asm volatile("s_waitcnt lgkmcnt(0)" ::: "memory");
    MFMA_Q(0, a0, b0);
    BARC();
    // ---- p6: read buf1 kk=1; stage (u+2)B1 ----
    #pragma unroll
    for (int m = 0; m < 8; ++m) a1[m] = ldA(1, m, 1);
    #pragma unroll
    for (int n = 0; n < 4; ++n) b1[n] = ldB(1, n, 1);
    if (more) stB(u + 2, 1);
    BARC();
    asm volatile("s_waitcnt lgkmcnt(0)" ::: "memory");
    MFMA_Q(1, a0, b0);
    BARC();
    // ---- p7: stage (u+3)A0 -> As[1].h0 (buf1 A reads done @p6) ----
    if (more) stA(u + 3, 0);
    BARC();
    MFMA_Q(0, a1, b1);
    BARC();
    // ---- p8: stage (u+3)A1; wait so tile u+2 landed before next p1 ----
    if (more) stA(u + 3, 1);
    BARC();
    MFMA_Q(1, a1, b1);
    if (more) { asm volatile("s_waitcnt vmcnt(4)" ::: "memory"); }
    BARC();
  }

  #pragma unroll
  for (int nt = 0; nt < 4; ++nt) {
    int col = bn * 256 + wn * 64 + nt * 16 + lane15;
    float bv = (bias && z0) ? bias[col] : 0.0f;
    #pragma unroll
    for (int mt = 0; mt < 8; ++mt) {
      int row0 = bm * 256 + wm * 128 + mt * 16 + quad * 4;
      #pragma unroll
      for (int r = 0; r < 4; ++r) {
        float val = acc[mt][nt][r] + bv;
        if (relu) val = fmaxf(val, 0.0f);
        if (resid && z0) val += resid[(size_t)(row0 + r) * N + col];
        store_out(&Co[(size_t)(row0 + r) * N + col], val);
      }
    }
  }
}

// ---- split-K combine: out = p0 + p1 (bias/resid folded into z=0) ------
__global__ __launch_bounds__(256) void add2(
    const float* __restrict__ p0, const float* __restrict__ p1,
    float* __restrict__ out)
{
  size_t i = ((size_t)blockIdx.x * 256 + threadIdx.x) * 4;
  float4 a = *(const float4*)(p0 + i);
  float4 b = *(const float4*)(p1 + i);
  *(float4*)(out + i) = make_float4(a.x + b.x, a.y + b.y, a.z + b.z, a.w + b.w);
}

// -------- MFMA flash attention v5 (v3 + causal key-range split) --------
// Block = 128 Q rows of one head (8 waves x 16 rows, 512 threads).
// No-max softmax in log2 domain -> partials over disjoint key ranges
// combine exactly by addition.  qblk >= 8 is split into two key-range
// halves (each <= 16 tiles, balancing the causal load); partial O (fp32)
// and l go to scratch, combined by attn_combine.
// blockIdx.x decode: bx<16 -> qblk=15-(bx>>1), half p=bx&1 (split);
//                    bx>=16 -> qblk=23-bx (unsplit).
__global__ __launch_bounds__(512) void attn_kernel(
    const unsigned short* __restrict__ qkv, const unsigned short* __restrict__ vt,
    unsigned short* __restrict__ attnb,
    float* __restrict__ opart0, float* __restrict__ opart1,
    float* __restrict__ lpart)
{
  __shared__ __align__(16) unsigned short Klds[64 * 64];   // [key][d]
  __shared__ __align__(16) unsigned short Vlds[64 * 64];   // [d][key]
  __shared__ __align__(16) unsigned short Plds[8][16 * 72];
  int tid = threadIdx.x, lane = tid & 63, widx = tid >> 6;
  int lane15 = lane & 15, quad = lane >> 4;

  int bx = blockIdx.x;
  int qblk, p, split;
  if (bx < 16) { qblk = 15 - (bx >> 1); p = bx & 1; split = 1; }
  else         { qblk = 23 - bx;        p = 0;      split = 0; }
  int ntiles = 2 * qblk + 2;
  int kt0 = (split && p) ? (qblk + 1) : 0;
  int kt1 = (split && !p) ? (qblk + 1) : ntiles;

  int bh = blockIdx.y;                   // 0..63
  int b = bh >> 4, h = bh & 15;
  int q0w = qblk * 128 + widx * 16;      // this wave's first Q row

  const float QSCALE = 0.18033688011112042f;  // 0.125 / ln(2)
  const unsigned short* qb = qkv + (size_t)(b * C_ + q0w + lane15) * 3072 + h * 64;
  bf16x8 qa0 = *(const bf16x8*)(qb + quad * 8);
  bf16x8 qa1 = *(const bf16x8*)(qb + 32 + quad * 8);
  #pragma unroll
  for (int j = 0; j < 8; ++j) {
    qa0[j] = (__bf16)((float)qa0[j] * QSCALE);
    qa1[j] = (__bf16)((float)qa1[j] * QSCALE);
  }

  float lsum[4];
  f32x4 o[4];
  #pragma unroll
  for (int r = 0; r < 4; ++r) lsum[r] = 0.0f;
  #pragma unroll
  for (int nt = 0; nt < 4; ++nt) o[nt] = 0.0f;

  int sr = tid >> 3, sc = tid & 7, sw = sr & 7;
  const unsigned short* kg = qkv + (size_t)(b * C_ + kt0 * 64 + sr) * 3072 + 1024 + h * 64 + (sc ^ sw) * 8;
  const unsigned short* vg = vt + (size_t)bh * 64 * 2048 + (size_t)sr * 2048 + (sc ^ sw) * 8 + kt0 * 64;
  unsigned short* kl = &Klds[sr * 64 + sc * 8];
  unsigned short* vl = &Vlds[sr * 64 + sc * 8];
  int swr = lane15 & 7;

  for (int kt = kt0; kt < kt1; ++kt) {
    int k0 = kt * 64;
    async16(kg, kl);
    async16(vg, vl);
    kg += (size_t)64 * 3072;
    vg += 64;
    __syncthreads();

    if (k0 <= q0w + 15) {
      f32x4 s[4];
      #pragma unroll
      for (int g = 0; g < 4; ++g) s[g] = 0.0f;
      #pragma unroll
      for (int g = 0; g < 4; ++g) {
        int row = g * 16 + lane15;
        bf16x8 kf0 = *(const bf16x8*)&Klds[row * 64 + ((quad ^ swr) * 8)];
        bf16x8 kf1 = *(const bf16x8*)&Klds[row * 64 + (((4 + quad) ^ swr) * 8)];
        s[g] = __builtin_amdgcn_mfma_f32_16x16x32_bf16(qa0, kf0, s[g], 0, 0, 0);
        s[g] = __builtin_amdgcn_mfma_f32_16x16x32_bf16(qa1, kf1, s[g], 0, 0, 0);
      }

      if (k0 + 63 > q0w) {
        #pragma unroll
        for (int g = 0; g < 4; ++g)
          #pragma unroll
          for (int r = 0; r < 4; ++r)
            if (k0 + g * 16 + lane15 > q0w + quad * 4 + r) s[g][r] = -3.0e38f;
      }

      float pv[4][4];
      #pragma unroll
      for (int g = 0; g < 4; ++g)
        #pragma unroll
        for (int r = 0; r < 4; ++r) pv[g][r] = exp2f(s[g][r]);
      #pragma unroll
      for (int r = 0; r < 4; ++r)
        lsum[r] += (pv[0][r] + pv[1][r]) + (pv[2][r] + pv[3][r]);

      __bf16* prow = (__bf16*)&Plds[widx][0];
      #pragma unroll
      for (int g = 0; g < 4; ++g)
        #pragma unroll
        for (int r = 0; r < 4; ++r)
          prow[(quad * 4 + r) * 72 + g * 16 + lane15] = (__bf16)pv[g][r];
      asm volatile("s_waitcnt lgkmcnt(0)" ::: "memory");
      bf16x8 pa0 = *(const bf16x8*)&Plds[widx][lane15 * 72 + quad * 8];
      bf16x8 pa1 = *(const bf16x8*)&Plds[widx][lane15 * 72 + 32 + quad * 8];

      #pragma unroll
      for (int nt = 0; nt < 4; ++nt) {
        int d = nt * 16 + lane15;
        bf16x8 vf0 = *(const bf16x8*)&Vlds[d * 64 + ((quad ^ swr) * 8)];
        bf16x8 vf1 = *(const bf16x8*)&Vlds[d * 64 + (((4 + quad) ^ swr) * 8)];
        o[nt] = __builtin_amdgcn_mfma_f32_16x16x32_bf16(pa0, vf0, o[nt], 0, 0, 0);
        o[nt] = __builtin_amdgcn_mfma_f32_16x16x32_bf16(pa1, vf1, o[nt], 0, 0, 0);
      }
    }
    __syncthreads();
  }

  #pragma unroll
  for (int off = 1; off <= 8; off <<= 1)
    #pragma unroll
    for (int r = 0; r < 4; ++r)
      lsum[r] += __shfl_xor(lsum[r], off);

  if (!split) {
    float rl[4];
    #pragma unroll
    for (int r = 0; r < 4; ++r) rl[r] = 1.0f / lsum[r];
    #pragma unroll
    for (int nt = 0; nt < 4; ++nt)
      #pragma unroll
      for (int r = 0; r < 4; ++r) {
        float val = o[nt][r] * rl[r];
        attnb[(size_t)(b * C_ + q0w + quad * 4 + r) * E_ + h * 64 + nt * 16 + lane15] = f2b(val);
      }
  } else {
    float* op = p ? opart1 : opart0;
    size_t rbase = (size_t)bh * 1024 + (q0w - 1024) + quad * 4;
    #pragma unroll
    for (int nt = 0; nt < 4; ++nt)
      #pragma unroll
      for (int r = 0; r < 4; ++r)
        op[(rbase + r) * 64 + nt * 16 + lane15] = o[nt][r];
    if (lane15 == 0) {
      float* lp = lpart + (size_t)p * 65536;
      #pragma unroll
      for (int r = 0; r < 4; ++r) lp[rbase + r] = lsum[r];
    }
  }
}

// combine split-attention partials: attnb = (O0+O1)/(l0+l1) for rows 1024+
__global__ __launch_bounds__(256) void attn_combine(
    const float* __restrict__ opart0, const float* __restrict__ opart1,
    const float* __restrict__ lpart, unsigned short* __restrict__ attnb)
{
  size_t i = (size_t)blockIdx.x * 256 + threadIdx.x;  // over 64*1024*64
  int d = (int)(i & 63);
  size_t rowi = i >> 6;                 // bh*1024 + row
  int bh = (int)(rowi >> 10), row = (int)(rowi & 1023);
  float ov = opart0[rowi * 64 + d] + opart1[rowi * 64 + d];
  float lv = lpart[rowi] + lpart[65536 + rowi];
  int b = bh >> 4, h = bh & 15;
  attnb[(size_t)(b * C_ + 1024 + row) * E_ + h * 64 + d] = f2b(ov / lv);
}

// ---------------------------- launcher ---------------------------------
extern "C" void kernel_launch(void* const* d_in, const int* in_sizes, int n_in,
                              void* d_out, int out_size, void* d_ws, size_t ws_size,
                              hipStream_t stream)
{
  const float* x   = (const float*)d_in[0];
  const float* Wq  = (const float*)d_in[1];
  const float* bq  = (const float*)d_in[2];
  const float* Wk  = (const float*)d_in[3];
  const float* bk  = (const float*)d_in[4];
  const float* Wv  = (const float*)d_in[5];
  const float* bv  = (const float*)d_in[6];
  const float* g1  = (const float*)d_in[7];
  const float* be1 = (const float*)d_in[8];
  const float* g2  = (const float*)d_in[9];
  const float* be2 = (const float*)d_in[10];
  const float* W1  = (const float*)d_in[11];
  const float* bm1 = (const float*)d_in[12];
  const float* W2  = (const float*)d_in[13];
  const float* bm2 = (const float*)d_in[14];

  char* ws = (char*)d_ws;
  // Region lifetime plan:
  //  [0,16M)      norm1 (LN1 out, dead after QKV gemm) -> lpart during attn
  //               -> norm2 (LN2 out) -> overlaid by part0 at MLP2
  //  [123.7M,+32M) free during attn -> opart1 -> out1 (LN2) 
  //  [165.7M,+32M) free during attn -> opart0 -> part1 (MLP2 z1)
  float*          part0 = (float*)(ws + 0);                   // 32 MB fp32 [8192][1024]
  unsigned short* norm1 = (unsigned short*)(ws + 0);          // 16 MB bf16 (reused as norm2)
  unsigned short* wT    = (unsigned short*)(ws + 16777216);   // 6 MB  bf16 WqkvT [3072][1024]
  unsigned short* w1T   = (unsigned short*)(ws + 23068672);   // 8 MB  bf16 [4096][1024]
  float*          biasq = (float*)(ws + 39845888);            // 12 KB fp32 [3072]
  unsigned short* qkv   = (unsigned short*)(ws + 39858176);   // 48 MB bf16 [8192][3072]
  unsigned short* vtb   = (unsigned short*)(ws + 90189824);   // 16 MB bf16 [64][64][2048]
  unsigned short* mid   = (unsigned short*)(ws + 39858176);   // 64 MB bf16 [8192][4096] (aliases qkv+vtb)
  unsigned short* attnb = (unsigned short*)(ws + 106967040);  // 16 MB bf16 [8192][1024]
  float*          out1  = (float*)(ws + 123744256);           // 32 MB fp32 [8192][1024]
  unsigned short* w2T   = (unsigned short*)(ws + 157298688);  // 8 MB  bf16 [1024][4096]
  float*          part1 = (float*)(ws + 165687296);           // 32 MB fp32 [8192][1024]
  // attn split partials (dead-region overlays, see plan above):
  float*          opart0 = (float*)(ws + 165687296);          // 16.78 MB
  float*          opart1 = (float*)(ws + 123744256);          // 16.78 MB
  float*          lpartb = (float*)(ws + 0);                  // 0.5 MB
  // total: 199,241,728 bytes
  size_t part_zs = ((size_t)165687296) / 4;                   // part1 - part0 in floats

  // weight transposes (+fp32->bf16 convert) -> [N][K]
  transpose64<float><<<dim3(16, 16, 1), 256, 0, stream>>>(Wq, wT,               1024, 1024, 1, 0, 0, 0);
  transpose64<float><<<dim3(16, 16, 1), 256, 0, stream>>>(Wk, wT + 1024 * 1024, 1024, 1024, 1, 0, 0, 0);
  transpose64<float><<<dim3(16, 16, 1), 256, 0, stream>>>(Wv, wT + 2048 * 1024, 1024, 1024, 1, 0, 0, 0);
  transpose64<float><<<dim3(64, 16, 1), 256, 0, stream>>>(W1, w1T, 4096, 1024, 1, 0, 0, 0);
  transpose64<float><<<dim3(16, 64, 1), 256, 0, stream>>>(W2, w2T, 1024, 4096, 1, 0, 0, 0);
  concat_bias<<<12, 256, 0, stream>>>(bq, bk, bv, biasq);

  // LN1: norm1 = LN(x) in bf16
  ln_kernel<<<ROWS_, 256, 0, stream>>>(x, nullptr, g1, be1, norm1, nullptr);

  // fused QKV GEMM: [8192][1024] @ [3072][1024]^T -> [8192][3072] bf16
  // grid = 32 M-blocks x 12 N-blocks = 384
  gemm256<unsigned short><<<dim3(384, 1, 1), 512, 0, stream>>>(
      norm1, wT, biasq, nullptr, qkv, 8192, 3072, 1024, 1024, 1024, 0, 0);

  // V^T per head: vt[b*H+h][d][c]
  transpose64<unsigned short><<<dim3(1, 32, 64), 256, 0, stream>>>(
      qkv + 2048, vtb, 3072, 2048, 16, (long)C_ * 3072, 64, (long)64 * 2048);

  // causal flash attention v5 (split heavy qblks)
  attn_kernel<<<dim3(24, 64), 512, 0, stream>>>(qkv, vtb, attnb, opart0, opart1, lpartb);
  attn_combine<<<16384, 256, 0, stream>>>(opart0, opart1, lpartb, attnb);

  // out1 = x + attn (fp32) ; norm2 = LN(out1) bf16
  ln_kernel<<<ROWS_, 256, 0, stream>>>(x, attnb, g2, be2, norm1, out1);

  // MLP1: relu(norm2 @ W1^T + bm1) -> mid bf16  (grid 32x16 = 512)
  gemm256<unsigned short><<<dim3(512, 1, 1), 512, 0, stream>>>(
      norm1, w1T, bm1, nullptr, mid, 8192, 4096, 1024, 1024, 1024, 1, 0);

  // MLP2 split-K: z=0 adds bm2+out1, z=1 raw partial (grid 32x4 x2)
  gemm256<float><<<dim3(128, 1, 2), 512, 0, stream>>>(
      mid, w2T, bm2, out1, part0, 8192, 1024, 2048, 4096, 4096, 0, part_zs);
  // out = part0 + part1
  add2<<<8192, 256, 0, stream>>>(part0, part1, (float*)d_out);
}

// Round 2
// 602.910 us; speedup vs baseline: 1.2664x; 1.2664x over previous
//
#include <hip/hip_runtime.h>
#include <math.h>

#define B_ 4
#define C_ 2048
#define E_ 1024
#define H_ 16
#define D_ 64
#define ROWS_ (B_*C_)   // 8192

typedef __bf16 bf16x8 __attribute__((ext_vector_type(8)));
typedef float f32x4 __attribute__((ext_vector_type(4)));

__device__ __forceinline__ float b2f(unsigned short u) {
  unsigned int x = ((unsigned int)u) << 16;
  return __builtin_bit_cast(float, x);
}
__device__ __forceinline__ unsigned short f2b(float f) {
  unsigned int x = __builtin_bit_cast(unsigned int, f);
  unsigned int r = (x + 0x7FFFu + ((x >> 16) & 1u)) >> 16;
  return (unsigned short)r;
}
__device__ __forceinline__ unsigned short tob(float f) { return f2b(f); }
__device__ __forceinline__ unsigned short tob(unsigned short u) { return u; }
__device__ __forceinline__ void store_out(float* p, float v) { *p = v; }
__device__ __forceinline__ void store_out(unsigned short* p, float v) { *p = f2b(v); }

__device__ __forceinline__ void async16(const void* g, void* l) {
  __builtin_amdgcn_global_load_lds(
      (__attribute__((address_space(1))) unsigned int*)g,
      (__attribute__((address_space(3))) unsigned int*)l, 16, 0, 0);
}

// ------------- 64x64 tiled transpose, InT -> bf16 ----------------------
template <typename InT>
__global__ __launch_bounds__(256) void transpose64(
    const InT* __restrict__ in, unsigned short* __restrict__ out,
    int s_in, int s_out, int Hz, long zs_b, long zs_h, long zs_out)
{
  __shared__ unsigned short t[64][65];
  int z = blockIdx.z;
  long ib = (long)(z / Hz) * zs_b + (long)(z % Hz) * zs_h;
  long ob = (long)z * zs_out;
  int r0 = blockIdx.y * 64, c0 = blockIdx.x * 64;
  int lane = threadIdx.x & 63, grp = threadIdx.x >> 6;
  for (int i = grp; i < 64; i += 4)
    t[i][lane] = tob(in[ib + (long)(r0 + i) * s_in + c0 + lane]);
  __syncthreads();
  for (int i = grp; i < 64; i += 4)
    out[ob + (long)(c0 + i) * s_out + r0 + lane] = t[lane][i];
}

__global__ void concat_bias(const float* __restrict__ q,
                            const float* __restrict__ k,
                            const float* __restrict__ v,
                            float* __restrict__ o)
{
  int i = blockIdx.x * 256 + threadIdx.x;  // 3072 total
  o[i] = (i < 1024) ? q[i] : (i < 2048) ? k[i - 1024] : v[i - 2048];
}

// ---------------- LayerNorm (optionally fused residual add) ------------
__global__ __launch_bounds__(256) void ln_kernel(
    const float* __restrict__ xin, const unsigned short* __restrict__ addend,
    const float* __restrict__ g, const float* __restrict__ beta,
    unsigned short* __restrict__ yout, float* __restrict__ out1)
{
  int row = blockIdx.x, tid = threadIdx.x;
  size_t base = (size_t)row * E_ + tid * 4;
  float4 xa = *(const float4*)(xin + base);
  float v0 = xa.x, v1 = xa.y, v2 = xa.z, v3 = xa.w;
  if (addend) {
    ushort4 aa = *(const ushort4*)(addend + base);
    v0 += b2f(aa.x); v1 += b2f(aa.y); v2 += b2f(aa.z); v3 += b2f(aa.w);
  }
  if (out1) {
    *(float4*)(out1 + base) = make_float4(v0, v1, v2, v3);
  }
  float s = v0 + v1 + v2 + v3;
  float sq = v0*v0 + v1*v1 + v2*v2 + v3*v3;
  #pragma unroll
  for (int off = 32; off >= 1; off >>= 1) {
    s  += __shfl_xor(s, off);
    sq += __shfl_xor(sq, off);
  }
  __shared__ float red[8];
  int wid = tid >> 6;
  if ((tid & 63) == 0) { red[wid] = s; red[4 + wid] = sq; }
  __syncthreads();
  s  = red[0] + red[1] + red[2] + red[3];
  sq = red[4] + red[5] + red[6] + red[7];
  float mu = s * (1.0f / E_);
  float var = sq * (1.0f / E_) - mu * mu;
  float rs = rsqrtf(var + 1e-5f);
  float4 ga = *(const float4*)(g + tid * 4);
  float4 ba = *(const float4*)(beta + tid * 4);
  ushort4 o;
  o.x = f2b((v0 - mu) * rs * ga.x + ba.x);
  o.y = f2b((v1 - mu) * rs * ga.y + ba.y);
  o.z = f2b((v2 - mu) * rs * ga.z + ba.z);
  o.w = f2b((v3 - mu) * rs * ga.w + ba.w);
  *(ushort4*)(yout + base) = o;
}

// ================ 256x256 BK=32 2-phase bf16 GEMM ======================
// C = A @ Bt^T (+bias)(+relu)(+resid on z==0).  BM=BN=256, BK=32,
// 8 waves (2M x 4N), per-wave 128x64 output (acc[8][4] f32x4 = 128 AGPR).
// LDS 64 KiB: As/Bs[2][256*32] — buffer parity = tile parity (t&1).
// Per K-tile t, two phases:
//   P1: 12 ds_read_b128 (af[8]+bfr[4], 48 VGPR live) -> bar ->
//       lgkmcnt(0) -> 16 MFMA (mh0) -> bar
//   P2: 4x global_load_lds staging tile t+2 (WAR-safe: all buffer-(t&1)
//       reads were issued in P1 and completed before every wave passed
//       P1's end barrier) -> 16 MFMA (mh1) -> s_waitcnt vmcnt(4) -> bar
// vmcnt(4): outstanding = tile t+1 (4 loads, issued @P2(t-1)) + tile t+2
// (4, just issued) = 8 -> retires tile t+1 exactly before P1(t+1) reads
// it; 4 loads always remain in flight (never drains in main loop).
// Swizzle: 4 col-slots, read slot = quad ^ rsw with
// rsw = (lane15&3)^(lane15>>2)  (<=2-way bank aliasing = free);
// stage applies the same involution on the GLOBAL source column while the
// LDS dest stays linear in tid (global_load_lds constraint).
#define BARC() { asm volatile("" ::: "memory"); __builtin_amdgcn_s_barrier(); asm volatile("" ::: "memory"); }

#define MFMA_HALF(mh) do {                                                  \
  __builtin_amdgcn_s_setprio(1);                                            \
  _Pragma("unroll")                                                         \
  for (int mt_ = 0; mt_ < 4; ++mt_)                                         \
    _Pragma("unroll")                                                       \
    for (int nt_ = 0; nt_ < 4; ++nt_)                                       \
      acc[(mh)*4+mt_][nt_] = __builtin_amdgcn_mfma_f32_16x16x32_bf16(       \
          af[(mh)*4+mt_], bfr[nt_], acc[(mh)*4+mt_][nt_], 0, 0, 0);         \
  __builtin_amdgcn_s_setprio(0);                                            \
} while (0)

template <typename OutT>
__global__ __launch_bounds__(512, 2) void gemm256(
    const unsigned short* __restrict__ A, const unsigned short* __restrict__ Bt,
    const float* __restrict__ bias, const float* __restrict__ resid,
    OutT* __restrict__ Co, int M, int N, int K, int lda, int ldb,
    int relu, size_t zs)
{
  __shared__ __align__(16) unsigned short As[2][256 * 32];   // 16 KiB each
  __shared__ __align__(16) unsigned short Bs[2][256 * 32];
  int tid = threadIdx.x, lane = tid & 63, wid = tid >> 6;
  int lane15 = lane & 15, quad = lane >> 4;
  int wm = wid >> 2, wn = wid & 3;

  // XCD-chunked block swizzle (M/256 == 32 assumed)
  int i = blockIdx.x;
  int xcd = i & 7, c = i >> 3;
  int bm = xcd * 4 + (c & 3);
  int bn = c >> 2;
  size_t koff = (size_t)blockIdx.z * K;
  int z0 = (blockIdx.z == 0);
  Co += (size_t)blockIdx.z * zs;

  // staging map: thread -> (row r = tid>>2 in 0..127 (+128h), slot tid&3)
  // LDS byte offset = tid*16 (linear); global col-group pre-swizzled.
  int sr2 = tid >> 2, s2 = tid & 3;
  int gcolg = s2 ^ ((tid >> 2) & 3) ^ ((tid >> 4) & 3);  // s ^ swz(r)
  const unsigned short* Ag = A + koff + (size_t)(bm * 256 + sr2) * lda + gcolg * 8;
  const unsigned short* Bg = Bt + koff + (size_t)(bn * 256 + sr2) * ldb + gcolg * 8;
  int dstb = wid * 512;                          // wave-uniform LDS base (ushorts)

  int NT = K >> 5;                               // 32-wide K tiles (>=2)

  f32x4 acc[8][4];
  #pragma unroll
  for (int m = 0; m < 8; ++m)
    #pragma unroll
    for (int n = 0; n < 4; ++n) acc[m][n] = 0.0f;

  auto stA = [&](int kt, int h) {
    async16(Ag + (size_t)(h * 128) * lda + kt * 32,
            &As[kt & 1][h * 4096 + dstb]);
  };
  auto stB = [&](int kt, int h) {
    async16(Bg + (size_t)(h * 128) * ldb + kt * 32,
            &Bs[kt & 1][h * 4096 + dstb]);
  };
  int rdoff = ((quad ^ ((lane15 & 3) ^ (lane15 >> 2))) * 8);  // read slot bytes/2

  // prologue: tiles 0 and 1 (4 loads each); tile0 must land, tile1 in flight
  stA(0, 0); stA(0, 1); stB(0, 0); stB(0, 1);
  stA(1, 0); stA(1, 1); stB(1, 0); stB(1, 1);
  asm volatile("s_waitcnt vmcnt(4)" ::: "memory");
  __builtin_amdgcn_s_barrier();

  for (int t = 0; t < NT; ++t) {
    const unsigned short* Ab = &As[t & 1][0];
    const unsigned short* Bb = &Bs[t & 1][0];
    bool more = (t + 2 < NT);
    bf16x8 af[8], bfr[4];
    // ---- P1: reads ----
    #pragma unroll
    for (int m = 0; m < 8; ++m)
      af[m] = *(const bf16x8*)&Ab[(wm * 128 + m * 16 + lane15) * 32 + rdoff];
    #pragma unroll
    for (int n = 0; n < 4; ++n)
      bfr[n] = *(const bf16x8*)&Bb[(wn * 64 + n * 16 + lane15) * 32 + rdoff];
    BARC();
    asm volatile("s_waitcnt lgkmcnt(0)" ::: "memory");
    MFMA_HALF(0);
    BARC();
    // ---- P2: stage tile t+2 into this buffer (reads all done @P1) ----
    if (more) { stA(t + 2, 0); stA(t + 2, 1); stB(t + 2, 0); stB(t + 2, 1); }
    MFMA_HALF(1);
    if (more) { asm volatile("s_waitcnt vmcnt(4)" ::: "memory"); }
    else      { asm volatile("s_waitcnt vmcnt(0)" ::: "memory"); }
    BARC();
  }

  #pragma unroll
  for (int nt = 0; nt < 4; ++nt) {
    int col = bn * 256 + wn * 64 + nt * 16 + lane15;
    float bv = (bias && z0) ? bias[col] : 0.0f;
    #pragma unroll
    for (int mt = 0; mt < 8; ++mt) {
      int row0 = bm * 256 + wm * 128 + mt * 16 + quad * 4;
      #pragma unroll
      for (int r = 0; r < 4; ++r) {
        float val = acc[mt][nt][r] + bv;
        if (relu) val = fmaxf(val, 0.0f);
        if (resid && z0) val += resid[(size_t)(row0 + r) * N + col];
        store_out(&Co[(size_t)(row0 + r) * N + col], val);
      }
    }
  }
}

// ---- split-K combine: out = p0 + p1 (bias/resid folded into z=0) ------
__global__ __launch_bounds__(256) void add2(
    const float* __restrict__ p0, const float* __restrict__ p1,
    float* __restrict__ out)
{
  size_t i = ((size_t)blockIdx.x * 256 + threadIdx.x) * 4;
  float4 a = *(const float4*)(p0 + i);
  float4 b = *(const float4*)(p1 + i);
  *(float4*)(out + i) = make_float4(a.x + b.x, a.y + b.y, a.z + b.z, a.w + b.w);
}

// -------- MFMA flash attention v5 (v3 + causal key-range split) --------
// Block = 128 Q rows of one head (8 waves x 16 rows, 512 threads).
// No-max softmax in log2 domain -> partials over disjoint key ranges
// combine exactly by addition.  qblk >= 8 is split into two key-range
// halves (each <= 16 tiles, balancing the causal load); partial O (fp32)
// and l go to scratch, combined by attn_combine.
// blockIdx.x decode: bx<16 -> qblk=15-(bx>>1), half p=bx&1 (split);
//                    bx>=16 -> qblk=23-bx (unsplit).
__global__ __launch_bounds__(512) void attn_kernel(
    const unsigned short* __restrict__ qkv, const unsigned short* __restrict__ vt,
    unsigned short* __restrict__ attnb,
    float* __restrict__ opart0, float* __restrict__ opart1,
    float* __restrict__ lpart)
{
  __shared__ __align__(16) unsigned short Klds[64 * 64];   // [key][d]
  __shared__ __align__(16) unsigned short Vlds[64 * 64];   // [d][key]
  __shared__ __align__(16) unsigned short Plds[8][16 * 72];
  int tid = threadIdx.x, lane = tid & 63, widx = tid >> 6;
  int lane15 = lane & 15, quad = lane >> 4;

  int bx = blockIdx.x;
  int qblk, p, split;
  if (bx < 16) { qblk = 15 - (bx >> 1); p = bx & 1; split = 1; }
  else         { qblk = 23 - bx;        p = 0;      split = 0; }
  int ntiles = 2 * qblk + 2;
  int kt0 = (split && p) ? (qblk + 1) : 0;
  int kt1 = (split && !p) ? (qblk + 1) : ntiles;

  int bh = blockIdx.y;                   // 0..63
  int b = bh >> 4, h = bh & 15;
  int q0w = qblk * 128 + widx * 16;      // this wave's first Q row

  const float QSCALE = 0.18033688011112042f;  // 0.125 / ln(2)
  const unsigned short* qb = qkv + (size_t)(b * C_ + q0w + lane15) * 3072 + h * 64;
  bf16x8 qa0 = *(const bf16x8*)(qb + quad * 8);
  bf16x8 qa1 = *(const bf16x8*)(qb + 32 + quad * 8);
  #pragma unroll
  for (int j = 0; j < 8; ++j) {
    qa0[j] = (__bf16)((float)qa0[j] * QSCALE);
    qa1[j] = (__bf16)((float)qa1[j] * QSCALE);
  }

  float lsum[4];
  f32x4 o[4];
  #pragma unroll
  for (int r = 0; r < 4; ++r) lsum[r] = 0.0f;
  #pragma unroll
  for (int nt = 0; nt < 4; ++nt) o[nt] = 0.0f;

  int sr = tid >> 3, sc = tid & 7, sw = sr & 7;
  const unsigned short* kg = qkv + (size_t)(b * C_ + kt0 * 64 + sr) * 3072 + 1024 + h * 64 + (sc ^ sw) * 8;
  const unsigned short* vg = vt + (size_t)bh * 64 * 2048 + (size_t)sr * 2048 + (sc ^ sw) * 8 + kt0 * 64;
  unsigned short* kl = &Klds[sr * 64 + sc * 8];
  unsigned short* vl = &Vlds[sr * 64 + sc * 8];
  int swr = lane15 & 7;

  for (int kt = kt0; kt < kt1; ++kt) {
    int k0 = kt * 64;
    async16(kg, kl);
    async16(vg, vl);
    kg += (size_t)64 * 3072;
    vg += 64;
    __syncthreads();

    if (k0 <= q0w + 15) {
      f32x4 s[4];
      #pragma unroll
      for (int g = 0; g < 4; ++g) s[g] = 0.0f;
      #pragma unroll
      for (int g = 0; g < 4; ++g) {
        int row = g * 16 + lane15;
        bf16x8 kf0 = *(const bf16x8*)&Klds[row * 64 + ((quad ^ swr) * 8)];
        bf16x8 kf1 = *(const bf16x8*)&Klds[row * 64 + (((4 + quad) ^ swr) * 8)];
        s[g] = __builtin_amdgcn_mfma_f32_16x16x32_bf16(qa0, kf0, s[g], 0, 0, 0);
        s[g] = __builtin_amdgcn_mfma_f32_16x16x32_bf16(qa1, kf1, s[g], 0, 0, 0);
      }

      if (k0 + 63 > q0w) {
        #pragma unroll
        for (int g = 0; g < 4; ++g)
          #pragma unroll
          for (int r = 0; r < 4; ++r)
            if (k0 + g * 16 + lane15 > q0w + quad * 4 + r) s[g][r] = -3.0e38f;
      }

      float pv[4][4];
      #pragma unroll
      for (int g = 0; g < 4; ++g)
        #pragma unroll
        for (int r = 0; r < 4; ++r) pv[g][r] = exp2f(s[g][r]);
      #pragma unroll
      for (int r = 0; r < 4; ++r)
        lsum[r] += (pv[0][r] + pv[1][r]) + (pv[2][r] + pv[3][r]);

      __bf16* prow = (__bf16*)&Plds[widx][0];
      #pragma unroll
      for (int g = 0; g < 4; ++g)
        #pragma unroll
        for (int r = 0; r < 4; ++r)
          prow[(quad * 4 + r) * 72 + g * 16 + lane15] = (__bf16)pv[g][r];
      asm volatile("s_waitcnt lgkmcnt(0)" ::: "memory");
      bf16x8 pa0 = *(const bf16x8*)&Plds[widx][lane15 * 72 + quad * 8];
      bf16x8 pa1 = *(const bf16x8*)&Plds[widx][lane15 * 72 + 32 + quad * 8];

      #pragma unroll
      for (int nt = 0; nt < 4; ++nt) {
        int d = nt * 16 + lane15;
        bf16x8 vf0 = *(const bf16x8*)&Vlds[d * 64 + ((quad ^ swr) * 8)];
        bf16x8 vf1 = *(const bf16x8*)&Vlds[d * 64 + (((4 + quad) ^ swr) * 8)];
        o[nt] = __builtin_amdgcn_mfma_f32_16x16x32_bf16(pa0, vf0, o[nt], 0, 0, 0);
        o[nt] = __builtin_amdgcn_mfma_f32_16x16x32_bf16(pa1, vf1, o[nt], 0, 0, 0);
      }
    }
    __syncthreads();
  }

  #pragma unroll
  for (int off = 1; off <= 8; off <<= 1)
    #pragma unroll
    for (int r = 0; r < 4; ++r)
      lsum[r] += __shfl_xor(lsum[r], off);

  if (!split) {
    float rl[4];
    #pragma unroll
    for (int r = 0; r < 4; ++r) rl[r] = 1.0f / lsum[r];
    #pragma unroll
    for (int nt = 0; nt < 4; ++nt)
      #pragma unroll
      for (int r = 0; r < 4; ++r) {
        float val = o[nt][r] * rl[r];
        attnb[(size_t)(b * C_ + q0w + quad * 4 + r) * E_ + h * 64 + nt * 16 + lane15] = f2b(val);
      }
  } else {
    float* op = p ? opart1 : opart0;
    size_t rbase = (size_t)bh * 1024 + (q0w - 1024) + quad * 4;
    #pragma unroll
    for (int nt = 0; nt < 4; ++nt)
      #pragma unroll
      for (int r = 0; r < 4; ++r)
        op[(rbase + r) * 64 + nt * 16 + lane15] = o[nt][r];
    if (lane15 == 0) {
      float* lp = lpart + (size_t)p * 65536;
      #pragma unroll
      for (int r = 0; r < 4; ++r) lp[rbase + r] = lsum[r];
    }
  }
}

// combine split-attention partials: attnb = (O0+O1)/(l0+l1) for rows 1024+
__global__ __launch_bounds__(256) void attn_combine(
    const float* __restrict__ opart0, const float* __restrict__ opart1,
    const float* __restrict__ lpart, unsigned short* __restrict__ attnb)
{
  size_t i = (size_t)blockIdx.x * 256 + threadIdx.x;  // over 64*1024*64
  int d = (int)(i & 63);
  size_t rowi = i >> 6;                 // bh*1024 + row
  int bh = (int)(rowi >> 10), row = (int)(rowi & 1023);
  float ov = opart0[rowi * 64 + d] + opart1[rowi * 64 + d];
  float lv = lpart[rowi] + lpart[65536 + rowi];
  int b = bh >> 4, h = bh & 15;
  attnb[(size_t)(b * C_ + 1024 + row) * E_ + h * 64 + d] = f2b(ov / lv);
}

// ---------------------------- launcher ---------------------------------
extern "C" void kernel_launch(void* const* d_in, const int* in_sizes, int n_in,
                              void* d_out, int out_size, void* d_ws, size_t ws_size,
                              hipStream_t stream)
{
  const float* x   = (const float*)d_in[0];
  const float* Wq  = (const float*)d_in[1];
  const float* bq  = (const float*)d_in[2];
  const float* Wk  = (const float*)d_in[3];
  const float* bk  = (const float*)d_in[4];
  const float* Wv  = (const float*)d_in[5];
  const float* bv  = (const float*)d_in[6];
  const float* g1  = (const float*)d_in[7];
  const float* be1 = (const float*)d_in[8];
  const float* g2  = (const float*)d_in[9];
  const float* be2 = (const float*)d_in[10];
  const float* W1  = (const float*)d_in[11];
  const float* bm1 = (const float*)d_in[12];
  const float* W2  = (const float*)d_in[13];
  const float* bm2 = (const float*)d_in[14];

  char* ws = (char*)d_ws;
  // Region lifetime plan:
  //  [0,16M)      norm1 (LN1 out, dead after QKV gemm) -> lpart during attn
  //               -> norm2 (LN2 out) -> overlaid by part0 at MLP2
  //  [123.7M,+32M) free during attn -> opart1 -> out1 (LN2) 
  //  [165.7M,+32M) free during attn -> opart0 -> part1 (MLP2 z1)
  float*          part0 = (float*)(ws + 0);                   // 32 MB fp32 [8192][1024]
  unsigned short* norm1 = (unsigned short*)(ws + 0);          // 16 MB bf16 (reused as norm2)
  unsigned short* wT    = (unsigned short*)(ws + 16777216);   // 6 MB  bf16 WqkvT [3072][1024]
  unsigned short* w1T   = (unsigned short*)(ws + 23068672);   // 8 MB  bf16 [4096][1024]
  float*          biasq = (float*)(ws + 39845888);            // 12 KB fp32 [3072]
  unsigned short* qkv   = (unsigned short*)(ws + 39858176);   // 48 MB bf16 [8192][3072]
  unsigned short* vtb   = (unsigned short*)(ws + 90189824);   // 16 MB bf16 [64][64][2048]
  unsigned short* mid   = (unsigned short*)(ws + 39858176);   // 64 MB bf16 [8192][4096] (aliases qkv+vtb)
  unsigned short* attnb = (unsigned short*)(ws + 106967040);  // 16 MB bf16 [8192][1024]
  float*          out1  = (float*)(ws + 123744256);           // 32 MB fp32 [8192][1024]
  unsigned short* w2T   = (unsigned short*)(ws + 157298688);  // 8 MB  bf16 [1024][4096]
  float*          part1 = (float*)(ws + 165687296);           // 32 MB fp32 [8192][1024]
  // attn split partials (dead-region overlays, see plan above):
  float*          opart0 = (float*)(ws + 165687296);          // 16.78 MB
  float*          opart1 = (float*)(ws + 123744256);          // 16.78 MB
  float*          lpartb = (float*)(ws + 0);                  // 0.5 MB
  // total: 199,241,728 bytes
  size_t part_zs = ((size_t)165687296) / 4;                   // part1 - part0 in floats

  // weight transposes (+fp32->bf16 convert) -> [N][K]
  transpose64<float><<<dim3(16, 16, 1), 256, 0, stream>>>(Wq, wT,               1024, 1024, 1, 0, 0, 0);
  transpose64<float><<<dim3(16, 16, 1), 256, 0, stream>>>(Wk, wT + 1024 * 1024, 1024, 1024, 1, 0, 0, 0);
  transpose64<float><<<dim3(16, 16, 1), 256, 0, stream>>>(Wv, wT + 2048 * 1024, 1024, 1024, 1, 0, 0, 0);
  transpose64<float><<<dim3(64, 16, 1), 256, 0, stream>>>(W1, w1T, 4096, 1024, 1, 0, 0, 0);
  transpose64<float><<<dim3(16, 64, 1), 256, 0, stream>>>(W2, w2T, 1024, 4096, 1, 0, 0, 0);
  concat_bias<<<12, 256, 0, stream>>>(bq, bk, bv, biasq);

  // LN1: norm1 = LN(x) in bf16
  ln_kernel<<<ROWS_, 256, 0, stream>>>(x, nullptr, g1, be1, norm1, nullptr);

  // fused QKV GEMM: [8192][1024] @ [3072][1024]^T -> [8192][3072] bf16
  // grid = 32 M-blocks x 12 N-blocks = 384
  gemm256<unsigned short><<<dim3(384, 1, 1), 512, 0, stream>>>(
      norm1, wT, biasq, nullptr, qkv, 8192, 3072, 1024, 1024, 1024, 0, 0);

  // V^T per head: vt[b*H+h][d][c]
  transpose64<unsigned short><<<dim3(1, 32, 64), 256, 0, stream>>>(
      qkv + 2048, vtb, 3072, 2048, 16, (long)C_ * 3072, 64, (long)64 * 2048);

  // causal flash attention v5 (split heavy qblks)
  attn_kernel<<<dim3(24, 64), 512, 0, stream>>>(qkv, vtb, attnb, opart0, opart1, lpartb);
  attn_combine<<<16384, 256, 0, stream>>>(opart0, opart1, lpartb, attnb);

  // out1 = x + attn (fp32) ; norm2 = LN(out1) bf16
  ln_kernel<<<ROWS_, 256, 0, stream>>>(x, attnb, g2, be2, norm1, out1);

  // MLP1: relu(norm2 @ W1^T + bm1) -> mid bf16  (grid 32x16 = 512)
  gemm256<unsigned short><<<dim3(512, 1, 1), 512, 0, stream>>>(
      norm1, w1T, bm1, nullptr, mid, 8192, 4096, 1024, 1024, 1024, 1, 0);

  // MLP2 split-K: z=0 adds bm2+out1, z=1 raw partial (grid 32x4 x2)
  gemm256<float><<<dim3(128, 1, 2), 512, 0, stream>>>(
      mid, w2T, bm2, out1, part0, 8192, 1024, 2048, 4096, 4096, 0, part_zs);
  // out = part0 + part1
  add2<<<8192, 256, 0, stream>>>(part0, part1, (float*)d_out);
}

// Round 3
// 565.871 us; speedup vs baseline: 1.3493x; 1.0655x over previous
//
#include <hip/hip_runtime.h>
#include <math.h>

#define B_ 4
#define C_ 2048
#define E_ 1024
#define H_ 16
#define D_ 64
#define ROWS_ (B_*C_)   // 8192

typedef __bf16 bf16x8 __attribute__((ext_vector_type(8)));
typedef float f32x4 __attribute__((ext_vector_type(4)));

__device__ __forceinline__ float b2f(unsigned short u) {
  unsigned int x = ((unsigned int)u) << 16;
  return __builtin_bit_cast(float, x);
}
__device__ __forceinline__ unsigned short f2b(float f) {
  unsigned int x = __builtin_bit_cast(unsigned int, f);
  unsigned int r = (x + 0x7FFFu + ((x >> 16) & 1u)) >> 16;
  return (unsigned short)r;
}
__device__ __forceinline__ unsigned short tob(float f) { return f2b(f); }
__device__ __forceinline__ unsigned short tob(unsigned short u) { return u; }
__device__ __forceinline__ void store_out(float* p, float v) { *p = v; }
__device__ __forceinline__ void store_out(unsigned short* p, float v) { *p = f2b(v); }

__device__ __forceinline__ void async16(const void* g, void* l) {
  __builtin_amdgcn_global_load_lds(
      (__attribute__((address_space(1))) unsigned int*)g,
      (__attribute__((address_space(3))) unsigned int*)l, 16, 0, 0);
}

// ------------- 64x64 tiled transpose, InT -> bf16 ----------------------
template <typename InT>
__global__ __launch_bounds__(256) void transpose64(
    const InT* __restrict__ in, unsigned short* __restrict__ out,
    int s_in, int s_out, int Hz, long zs_b, long zs_h, long zs_out)
{
  __shared__ unsigned short t[64][65];
  int z = blockIdx.z;
  long ib = (long)(z / Hz) * zs_b + (long)(z % Hz) * zs_h;
  long ob = (long)z * zs_out;
  int r0 = blockIdx.y * 64, c0 = blockIdx.x * 64;
  int lane = threadIdx.x & 63, grp = threadIdx.x >> 6;
  for (int i = grp; i < 64; i += 4)
    t[i][lane] = tob(in[ib + (long)(r0 + i) * s_in + c0 + lane]);
  __syncthreads();
  for (int i = grp; i < 64; i += 4)
    out[ob + (long)(c0 + i) * s_out + r0 + lane] = t[lane][i];
}

__global__ void concat_bias(const float* __restrict__ q,
                            const float* __restrict__ k,
                            const float* __restrict__ v,
                            float* __restrict__ o)
{
  int i = blockIdx.x * 256 + threadIdx.x;  // 3072 total
  o[i] = (i < 1024) ? q[i] : (i < 2048) ? k[i - 1024] : v[i - 2048];
}

// ---------------- LayerNorm (optionally fused residual add) ------------
__global__ __launch_bounds__(256) void ln_kernel(
    const float* __restrict__ xin, const unsigned short* __restrict__ addend,
    const float* __restrict__ g, const float* __restrict__ beta,
    unsigned short* __restrict__ yout, float* __restrict__ out1)
{
  int row = blockIdx.x, tid = threadIdx.x;
  size_t base = (size_t)row * E_ + tid * 4;
  float4 xa = *(const float4*)(xin + base);
  float v0 = xa.x, v1 = xa.y, v2 = xa.z, v3 = xa.w;
  if (addend) {
    ushort4 aa = *(const ushort4*)(addend + base);
    v0 += b2f(aa.x); v1 += b2f(aa.y); v2 += b2f(aa.z); v3 += b2f(aa.w);
  }
  if (out1) {
    *(float4*)(out1 + base) = make_float4(v0, v1, v2, v3);
  }
  float s = v0 + v1 + v2 + v3;
  float sq = v0*v0 + v1*v1 + v2*v2 + v3*v3;
  #pragma unroll
  for (int off = 32; off >= 1; off >>= 1) {
    s  += __shfl_xor(s, off);
    sq += __shfl_xor(sq, off);
  }
  __shared__ float red[8];
  int wid = tid >> 6;
  if ((tid & 63) == 0) { red[wid] = s; red[4 + wid] = sq; }
  __syncthreads();
  s  = red[0] + red[1] + red[2] + red[3];
  sq = red[4] + red[5] + red[6] + red[7];
  float mu = s * (1.0f / E_);
  float var = sq * (1.0f / E_) - mu * mu;
  float rs = rsqrtf(var + 1e-5f);
  float4 ga = *(const float4*)(g + tid * 4);
  float4 ba = *(const float4*)(beta + tid * 4);
  ushort4 o;
  o.x = f2b((v0 - mu) * rs * ga.x + ba.x);
  o.y = f2b((v1 - mu) * rs * ga.y + ba.y);
  o.z = f2b((v2 - mu) * rs * ga.z + ba.z);
  o.w = f2b((v3 - mu) * rs * ga.w + ba.w);
  *(ushort4*)(yout + base) = o;
}

// ================ 256x256 BK=64 1-barrier-per-tile bf16 GEMM ===========
// C = A @ Bt^T (+bias)(+relu)(+resid on z==0).  BM=BN=256, BK=64,
// 8 waves (2M x 4N), per-wave 128x64 output (acc[8][4] f32x4 = 128 AGPR).
// LDS 128 KiB: As/Bs[2][256*64] double-buffered on tile parity.
// Per K-tile t:
//   top: stage tile t+1 into buf (t+1)&1 (8x global_load_lds; NEVER the
//        buffer being read this tile -> no WAR with reads of buf t&1).
//   4 read/MFMA phases (mh0/kk0, mh1/kk0, mh0/kk1, mh1/kk1), each
//   {4-8 ds_read_b128 -> 16 MFMA}, separated by sched_barrier(0) to
//   bound live fragments (<=12 b16x8 = 48 VGPR; R1's front-load spilled).
//   end: s_waitcnt vmcnt(0) (stage loads aged ~1 full tile >= HBM lat)
//        + s_barrier.  ONE barrier per 64-K: waves slip phases within
//        the tile so one wave's ds_reads overlap another's MFMA.
// WAR proof for the single barrier: every ds_read's consuming MFMA is
// before the tile-end barrier, so all reads of buf (t+1)&1 (done at tile
// t-1) completed before any wave stages into it at tile t's top.
// LDS geometry: row stride 64 ushorts = 128 B, 8x16B slots, slot XOR
// (row&7) swizzle -- identical to the R0 kernel measured at
// SQ_LDS_BANK_CONFLICT == 0 (the R2 64B-stride layout measured 4 cy/read).
#define BARC() { asm volatile("" ::: "memory"); __builtin_amdgcn_s_barrier(); asm volatile("" ::: "memory"); }

#define MFMA_Q(mh) do {                                                     \
  __builtin_amdgcn_s_setprio(1);                                            \
  _Pragma("unroll")                                                         \
  for (int mt_ = 0; mt_ < 4; ++mt_)                                         \
    _Pragma("unroll")                                                       \
    for (int nt_ = 0; nt_ < 4; ++nt_)                                       \
      acc[(mh)*4+mt_][nt_] = __builtin_amdgcn_mfma_f32_16x16x32_bf16(       \
          af[mt_], bfr[nt_], acc[(mh)*4+mt_][nt_], 0, 0, 0);                \
  __builtin_amdgcn_s_setprio(0);                                            \
} while (0)

template <typename OutT>
__global__ __launch_bounds__(512, 2) void gemm256(
    const unsigned short* __restrict__ A, const unsigned short* __restrict__ Bt,
    const float* __restrict__ bias, const float* __restrict__ resid,
    OutT* __restrict__ Co, int M, int N, int K, int lda, int ldb,
    int relu, size_t zs)
{
  __shared__ __align__(16) unsigned short As[2][256 * 64];   // 32 KiB each
  __shared__ __align__(16) unsigned short Bs[2][256 * 64];
  int tid = threadIdx.x, lane = tid & 63, wid = tid >> 6;
  int lane15 = lane & 15, quad = lane >> 4;
  int wm = wid >> 2, wn = wid & 3;

  // XCD-chunked block swizzle (M/256 == 32 assumed)
  int i = blockIdx.x;
  int xcd = i & 7, c = i >> 3;
  int bm = xcd * 4 + (c & 3);
  int bn = c >> 2;
  size_t koff = (size_t)blockIdx.z * K;
  int z0 = (blockIdx.z == 0);
  Co += (size_t)blockIdx.z * zs;

  // staging map: thread -> (row sr 0..63 per 64-row chunk, slot sc 0..7)
  // LDS dest linear (tid*16B within chunk); global col pre-swizzled.
  int sr = tid >> 3, sc = tid & 7;
  int gcol = (sc ^ (sr & 7)) * 8;                // ushort col in 64-wide tile
  const unsigned short* Ag = A + koff + (size_t)(bm * 256 + sr) * lda + gcol;
  const unsigned short* Bg = Bt + koff + (size_t)(bn * 256 + sr) * ldb + gcol;
  int dstb = wid * 512;                          // wave-uniform (ushorts)

  int NT = K >> 6;                               // 64-wide K tiles

  f32x4 acc[8][4];
  #pragma unroll
  for (int m = 0; m < 8; ++m)
    #pragma unroll
    for (int n = 0; n < 4; ++n) acc[m][n] = 0.0f;

  auto stage = [&](int kt) {
    unsigned short* Ad = &As[kt & 1][dstb];
    unsigned short* Bd = &Bs[kt & 1][dstb];
    const unsigned short* Asrc = Ag + kt * 64;
    const unsigned short* Bsrc = Bg + kt * 64;
    #pragma unroll
    for (int h = 0; h < 4; ++h) {
      async16(Asrc + (size_t)(h * 64) * lda, Ad + h * 4096);
      async16(Bsrc + (size_t)(h * 64) * ldb, Bd + h * 4096);
    }
  };
  int rsw = lane15 & 7;

  // prologue: tile 0 staged and landed
  stage(0);
  asm volatile("s_waitcnt vmcnt(0)" ::: "memory");
  __builtin_amdgcn_s_barrier();

  for (int t = 0; t < NT; ++t) {
    const unsigned short* Ab = &As[t & 1][0];
    const unsigned short* Bb = &Bs[t & 1][0];
    if (t + 1 < NT) stage(t + 1);
    __builtin_amdgcn_sched_barrier(0);
    bf16x8 af[4], bfr[4];
    // P1: mh0, kk0
    #pragma unroll
    for (int m = 0; m < 4; ++m)
      af[m] = *(const bf16x8*)&Ab[(wm * 128 + m * 16 + lane15) * 64 + ((quad ^ rsw) * 8)];
    #pragma unroll
    for (int n = 0; n < 4; ++n)
      bfr[n] = *(const bf16x8*)&Bb[(wn * 64 + n * 16 + lane15) * 64 + ((quad ^ rsw) * 8)];
    MFMA_Q(0);
    __builtin_amdgcn_sched_barrier(0);
    // P2: mh1, kk0 (bfr reused)
    #pragma unroll
    for (int m = 0; m < 4; ++m)
      af[m] = *(const bf16x8*)&Ab[(wm * 128 + 64 + m * 16 + lane15) * 64 + ((quad ^ rsw) * 8)];
    MFMA_Q(1);
    __builtin_amdgcn_sched_barrier(0);
    // P3: mh0, kk1
    #pragma unroll
    for (int m = 0; m < 4; ++m)
      af[m] = *(const bf16x8*)&Ab[(wm * 128 + m * 16 + lane15) * 64 + (((4 + quad) ^ rsw) * 8)];
    #pragma unroll
    for (int n = 0; n < 4; ++n)
      bfr[n] = *(const bf16x8*)&Bb[(wn * 64 + n * 16 + lane15) * 64 + (((4 + quad) ^ rsw) * 8)];
    MFMA_Q(0);
    __builtin_amdgcn_sched_barrier(0);
    // P4: mh1, kk1
    #pragma unroll
    for (int m = 0; m < 4; ++m)
      af[m] = *(const bf16x8*)&Ab[(wm * 128 + 64 + m * 16 + lane15) * 64 + (((4 + quad) ^ rsw) * 8)];
    MFMA_Q(1);
    // stage loads for t+1 were issued ~1 full tile ago (>= HBM latency)
    asm volatile("s_waitcnt vmcnt(0)" ::: "memory");
    BARC();
  }

  #pragma unroll
  for (int nt = 0; nt < 4; ++nt) {
    int col = bn * 256 + wn * 64 + nt * 16 + lane15;
    float bv = (bias && z0) ? bias[col] : 0.0f;
    #pragma unroll
    for (int mt = 0; mt < 8; ++mt) {
      int row0 = bm * 256 + wm * 128 + mt * 16 + quad * 4;
      #pragma unroll
      for (int r = 0; r < 4; ++r) {
        float val = acc[mt][nt][r] + bv;
        if (relu) val = fmaxf(val, 0.0f);
        if (resid && z0) val += resid[(size_t)(row0 + r) * N + col];
        store_out(&Co[(size_t)(row0 + r) * N + col], val);
      }
    }
  }
}

// ---- split-K combine: out = p0 + p1 (bias/resid folded into z=0) ------
__global__ __launch_bounds__(256) void add2(
    const float* __restrict__ p0, const float* __restrict__ p1,
    float* __restrict__ out)
{
  size_t i = ((size_t)blockIdx.x * 256 + threadIdx.x) * 4;
  float4 a = *(const float4*)(p0 + i);
  float4 b = *(const float4*)(p1 + i);
  *(float4*)(out + i) = make_float4(a.x + b.x, a.y + b.y, a.z + b.z, a.w + b.w);
}

// -------- MFMA flash attention v5 (v3 + causal key-range split) --------
// Block = 128 Q rows of one head (8 waves x 16 rows, 512 threads).
// No-max softmax in log2 domain -> partials over disjoint key ranges
// combine exactly by addition.  qblk >= 8 is split into two key-range
// halves (each <= 16 tiles, balancing the causal load); partial O (fp32)
// and l go to scratch, combined by attn_combine.
// blockIdx.x decode: bx<16 -> qblk=15-(bx>>1), half p=bx&1 (split);
//                    bx>=16 -> qblk=23-bx (unsplit).
__global__ __launch_bounds__(512) void attn_kernel(
    const unsigned short* __restrict__ qkv, const unsigned short* __restrict__ vt,
    unsigned short* __restrict__ attnb,
    float* __restrict__ opart0, float* __restrict__ opart1,
    float* __restrict__ lpart)
{
  __shared__ __align__(16) unsigned short Klds[64 * 64];   // [key][d]
  __shared__ __align__(16) unsigned short Vlds[64 * 64];   // [d][key]
  __shared__ __align__(16) unsigned short Plds[8][16 * 72];
  int tid = threadIdx.x, lane = tid & 63, widx = tid >> 6;
  int lane15 = lane & 15, quad = lane >> 4;

  int bx = blockIdx.x;
  int qblk, p, split;
  if (bx < 16) { qblk = 15 - (bx >> 1); p = bx & 1; split = 1; }
  else         { qblk = 23 - bx;        p = 0;      split = 0; }
  int ntiles = 2 * qblk + 2;
  int kt0 = (split && p) ? (qblk + 1) : 0;
  int kt1 = (split && !p) ? (qblk + 1) : ntiles;

  int bh = blockIdx.y;                   // 0..63
  int b = bh >> 4, h = bh & 15;
  int q0w = qblk * 128 + widx * 16;      // this wave's first Q row

  const float QSCALE = 0.18033688011112042f;  // 0.125 / ln(2)
  const unsigned short* qb = qkv + (size_t)(b * C_ + q0w + lane15) * 3072 + h * 64;
  bf16x8 qa0 = *(const bf16x8*)(qb + quad * 8);
  bf16x8 qa1 = *(const bf16x8*)(qb + 32 + quad * 8);
  #pragma unroll
  for (int j = 0; j < 8; ++j) {
    qa0[j] = (__bf16)((float)qa0[j] * QSCALE);
    qa1[j] = (__bf16)((float)qa1[j] * QSCALE);
  }

  float lsum[4];
  f32x4 o[4];
  #pragma unroll
  for (int r = 0; r < 4; ++r) lsum[r] = 0.0f;
  #pragma unroll
  for (int nt = 0; nt < 4; ++nt) o[nt] = 0.0f;

  int sr = tid >> 3, sc = tid & 7, sw = sr & 7;
  const unsigned short* kg = qkv + (size_t)(b * C_ + kt0 * 64 + sr) * 3072 + 1024 + h * 64 + (sc ^ sw) * 8;
  const unsigned short* vg = vt + (size_t)bh * 64 * 2048 + (size_t)sr * 2048 + (sc ^ sw) * 8 + kt0 * 64;
  unsigned short* kl = &Klds[sr * 64 + sc * 8];
  unsigned short* vl = &Vlds[sr * 64 + sc * 8];
  int swr = lane15 & 7;

  for (int kt = kt0; kt < kt1; ++kt) {
    int k0 = kt * 64;
    async16(kg, kl);
    async16(vg, vl);
    kg += (size_t)64 * 3072;
    vg += 64;
    __syncthreads();

    if (k0 <= q0w + 15) {
      f32x4 s[4];
      #pragma unroll
      for (int g = 0; g < 4; ++g) s[g] = 0.0f;
      #pragma unroll
      for (int g = 0; g < 4; ++g) {
        int row = g * 16 + lane15;
        bf16x8 kf0 = *(const bf16x8*)&Klds[row * 64 + ((quad ^ swr) * 8)];
        bf16x8 kf1 = *(const bf16x8*)&Klds[row * 64 + (((4 + quad) ^ swr) * 8)];
        s[g] = __builtin_amdgcn_mfma_f32_16x16x32_bf16(qa0, kf0, s[g], 0, 0, 0);
        s[g] = __builtin_amdgcn_mfma_f32_16x16x32_bf16(qa1, kf1, s[g], 0, 0, 0);
      }

      if (k0 + 63 > q0w) {
        #pragma unroll
        for (int g = 0; g < 4; ++g)
          #pragma unroll
          for (int r = 0; r < 4; ++r)
            if (k0 + g * 16 + lane15 > q0w + quad * 4 + r) s[g][r] = -3.0e38f;
      }

      float pv[4][4];
      #pragma unroll
      for (int g = 0; g < 4; ++g)
        #pragma unroll
        for (int r = 0; r < 4; ++r) pv[g][r] = exp2f(s[g][r]);
      #pragma unroll
      for (int r = 0; r < 4; ++r)
        lsum[r] += (pv[0][r] + pv[1][r]) + (pv[2][r] + pv[3][r]);

      __bf16* prow = (__bf16*)&Plds[widx][0];
      #pragma unroll
      for (int g = 0; g < 4; ++g)
        #pragma unroll
        for (int r = 0; r < 4; ++r)
          prow[(quad * 4 + r) * 72 + g * 16 + lane15] = (__bf16)pv[g][r];
      asm volatile("s_waitcnt lgkmcnt(0)" ::: "memory");
      bf16x8 pa0 = *(const bf16x8*)&Plds[widx][lane15 * 72 + quad * 8];
      bf16x8 pa1 = *(const bf16x8*)&Plds[widx][lane15 * 72 + 32 + quad * 8];

      #pragma unroll
      for (int nt = 0; nt < 4; ++nt) {
        int d = nt * 16 + lane15;
        bf16x8 vf0 = *(const bf16x8*)&Vlds[d * 64 + ((quad ^ swr) * 8)];
        bf16x8 vf1 = *(const bf16x8*)&Vlds[d * 64 + (((4 + quad) ^ swr) * 8)];
        o[nt] = __builtin_amdgcn_mfma_f32_16x16x32_bf16(pa0, vf0, o[nt], 0, 0, 0);
        o[nt] = __builtin_amdgcn_mfma_f32_16x16x32_bf16(pa1, vf1, o[nt], 0, 0, 0);
      }
    }
    __syncthreads();
  }

  #pragma unroll
  for (int off = 1; off <= 8; off <<= 1)
    #pragma unroll
    for (int r = 0; r < 4; ++r)
      lsum[r] += __shfl_xor(lsum[r], off);

  if (!split) {
    float rl[4];
    #pragma unroll
    for (int r = 0; r < 4; ++r) rl[r] = 1.0f / lsum[r];
    #pragma unroll
    for (int nt = 0; nt < 4; ++nt)
      #pragma unroll
      for (int r = 0; r < 4; ++r) {
        float val = o[nt][r] * rl[r];
        attnb[(size_t)(b * C_ + q0w + quad * 4 + r) * E_ + h * 64 + nt * 16 + lane15] = f2b(val);
      }
  } else {
    float* op = p ? opart1 : opart0;
    size_t rbase = (size_t)bh * 1024 + (q0w - 1024) + quad * 4;
    #pragma unroll
    for (int nt = 0; nt < 4; ++nt)
      #pragma unroll
      for (int r = 0; r < 4; ++r)
        op[(rbase + r) * 64 + nt * 16 + lane15] = o[nt][r];
    if (lane15 == 0) {
      float* lp = lpart + (size_t)p * 65536;
      #pragma unroll
      for (int r = 0; r < 4; ++r) lp[rbase + r] = lsum[r];
    }
  }
}

// combine split-attention partials: attnb = (O0+O1)/(l0+l1) for rows 1024+
__global__ __launch_bounds__(256) void attn_combine(
    const float* __restrict__ opart0, const float* __restrict__ opart1,
    const float* __restrict__ lpart, unsigned short* __restrict__ attnb)
{
  size_t i = (size_t)blockIdx.x * 256 + threadIdx.x;  // over 64*1024*64
  int d = (int)(i & 63);
  size_t rowi = i >> 6;                 // bh*1024 + row
  int bh = (int)(rowi >> 10), row = (int)(rowi & 1023);
  float ov = opart0[rowi * 64 + d] + opart1[rowi * 64 + d];
  float lv = lpart[rowi] + lpart[65536 + rowi];
  int b = bh >> 4, h = bh & 15;
  attnb[(size_t)(b * C_ + 1024 + row) * E_ + h * 64 + d] = f2b(ov / lv);
}

// ---------------------------- launcher ---------------------------------
extern "C" void kernel_launch(void* const* d_in, const int* in_sizes, int n_in,
                              void* d_out, int out_size, void* d_ws, size_t ws_size,
                              hipStream_t stream)
{
  const float* x   = (const float*)d_in[0];
  const float* Wq  = (const float*)d_in[1];
  const float* bq  = (const float*)d_in[2];
  const float* Wk  = (const float*)d_in[3];
  const float* bk  = (const float*)d_in[4];
  const float* Wv  = (const float*)d_in[5];
  const float* bv  = (const float*)d_in[6];
  const float* g1  = (const float*)d_in[7];
  const float* be1 = (const float*)d_in[8];
  const float* g2  = (const float*)d_in[9];
  const float* be2 = (const float*)d_in[10];
  const float* W1  = (const float*)d_in[11];
  const float* bm1 = (const float*)d_in[12];
  const float* W2  = (const float*)d_in[13];
  const float* bm2 = (const float*)d_in[14];

  char* ws = (char*)d_ws;
  // Region lifetime plan:
  //  [0,16M)      norm1 (LN1 out, dead after QKV gemm) -> lpart during attn
  //               -> norm2 (LN2 out) -> overlaid by part0 at MLP2
  //  [123.7M,+32M) free during attn -> opart1 -> out1 (LN2) 
  //  [165.7M,+32M) free during attn -> opart0 -> part1 (MLP2 z1)
  float*          part0 = (float*)(ws + 0);                   // 32 MB fp32 [8192][1024]
  unsigned short* norm1 = (unsigned short*)(ws + 0);          // 16 MB bf16 (reused as norm2)
  unsigned short* wT    = (unsigned short*)(ws + 16777216);   // 6 MB  bf16 WqkvT [3072][1024]
  unsigned short* w1T   = (unsigned short*)(ws + 23068672);   // 8 MB  bf16 [4096][1024]
  float*          biasq = (float*)(ws + 39845888);            // 12 KB fp32 [3072]
  unsigned short* qkv   = (unsigned short*)(ws + 39858176);   // 48 MB bf16 [8192][3072]
  unsigned short* vtb   = (unsigned short*)(ws + 90189824);   // 16 MB bf16 [64][64][2048]
  unsigned short* mid   = (unsigned short*)(ws + 39858176);   // 64 MB bf16 [8192][4096] (aliases qkv+vtb)
  unsigned short* attnb = (unsigned short*)(ws + 106967040);  // 16 MB bf16 [8192][1024]
  float*          out1  = (float*)(ws + 123744256);           // 32 MB fp32 [8192][1024]
  unsigned short* w2T   = (unsigned short*)(ws + 157298688);  // 8 MB  bf16 [1024][4096]
  float*          part1 = (float*)(ws + 165687296);           // 32 MB fp32 [8192][1024]
  // attn split partials (dead-region overlays, see plan above):
  float*          opart0 = (float*)(ws + 165687296);          // 16.78 MB
  float*          opart1 = (float*)(ws + 123744256);          // 16.78 MB
  float*          lpartb = (float*)(ws + 0);                  // 0.5 MB
  // total: 199,241,728 bytes
  size_t part_zs = ((size_t)165687296) / 4;                   // part1 - part0 in floats

  // weight transposes (+fp32->bf16 convert) -> [N][K]
  transpose64<float><<<dim3(16, 16, 1), 256, 0, stream>>>(Wq, wT,               1024, 1024, 1, 0, 0, 0);
  transpose64<float><<<dim3(16, 16, 1), 256, 0, stream>>>(Wk, wT + 1024 * 1024, 1024, 1024, 1, 0, 0, 0);
  transpose64<float><<<dim3(16, 16, 1), 256, 0, stream>>>(Wv, wT + 2048 * 1024, 1024, 1024, 1, 0, 0, 0);
  transpose64<float><<<dim3(64, 16, 1), 256, 0, stream>>>(W1, w1T, 4096, 1024, 1, 0, 0, 0);
  transpose64<float><<<dim3(16, 64, 1), 256, 0, stream>>>(W2, w2T, 1024, 4096, 1, 0, 0, 0);
  concat_bias<<<12, 256, 0, stream>>>(bq, bk, bv, biasq);

  // LN1: norm1 = LN(x) in bf16
  ln_kernel<<<ROWS_, 256, 0, stream>>>(x, nullptr, g1, be1, norm1, nullptr);

  // fused QKV GEMM: [8192][1024] @ [3072][1024]^T -> [8192][3072] bf16
  // grid = 32 M-blocks x 12 N-blocks = 384
  gemm256<unsigned short><<<dim3(384, 1, 1), 512, 0, stream>>>(
      norm1, wT, biasq, nullptr, qkv, 8192, 3072, 1024, 1024, 1024, 0, 0);

  // V^T per head: vt[b*H+h][d][c]
  transpose64<unsigned short><<<dim3(1, 32, 64), 256, 0, stream>>>(
      qkv + 2048, vtb, 3072, 2048, 16, (long)C_ * 3072, 64, (long)64 * 2048);

  // causal flash attention v5 (split heavy qblks)
  attn_kernel<<<dim3(24, 64), 512, 0, stream>>>(qkv, vtb, attnb, opart0, opart1, lpartb);
  attn_combine<<<16384, 256, 0, stream>>>(opart0, opart1, lpartb, attnb);

  // out1 = x + attn (fp32) ; norm2 = LN(out1) bf16
  ln_kernel<<<ROWS_, 256, 0, stream>>>(x, attnb, g2, be2, norm1, out1);

  // MLP1: relu(norm2 @ W1^T + bm1) -> mid bf16  (grid 32x16 = 512)
  gemm256<unsigned short><<<dim3(512, 1, 1), 512, 0, stream>>>(
      norm1, w1T, bm1, nullptr, mid, 8192, 4096, 1024, 1024, 1024, 1, 0);

  // MLP2 split-K: z=0 adds bm2+out1, z=1 raw partial (grid 32x4 x2)
  gemm256<float><<<dim3(128, 1, 2), 512, 0, stream>>>(
      mid, w2T, bm2, out1, part0, 8192, 1024, 2048, 4096, 4096, 0, part_zs);
  // out = part0 + part1
  add2<<<8192, 256, 0, stream>>>(part0, part1, (float*)d_out);
}

// Round 4
// 561.059 us; speedup vs baseline: 1.3609x; 1.0086x over previous
//
#include <hip/hip_runtime.h>
#include <math.h>

#define B_ 4
#define C_ 2048
#define E_ 1024
#define H_ 16
#define D_ 64
#define ROWS_ (B_*C_)   // 8192

typedef __bf16 bf16x8 __attribute__((ext_vector_type(8)));
typedef float f32x4 __attribute__((ext_vector_type(4)));

__device__ __forceinline__ float b2f(unsigned short u) {
  unsigned int x = ((unsigned int)u) << 16;
  return __builtin_bit_cast(float, x);
}
__device__ __forceinline__ unsigned short f2b(float f) {
  unsigned int x = __builtin_bit_cast(unsigned int, f);
  unsigned int r = (x + 0x7FFFu + ((x >> 16) & 1u)) >> 16;
  return (unsigned short)r;
}
__device__ __forceinline__ unsigned short tob(float f) { return f2b(f); }
__device__ __forceinline__ unsigned short tob(unsigned short u) { return u; }
__device__ __forceinline__ void store_out(float* p, float v) { *p = v; }
__device__ __forceinline__ void store_out(unsigned short* p, float v) { *p = f2b(v); }

__device__ __forceinline__ void async16(const void* g, void* l) {
  __builtin_amdgcn_global_load_lds(
      (__attribute__((address_space(1))) unsigned int*)g,
      (__attribute__((address_space(3))) unsigned int*)l, 16, 0, 0);
}

// ------------- 64x64 tiled transpose, InT -> bf16 ----------------------
template <typename InT>
__global__ __launch_bounds__(256) void transpose64(
    const InT* __restrict__ in, unsigned short* __restrict__ out,
    int s_in, int s_out, int Hz, long zs_b, long zs_h, long zs_out)
{
  __shared__ unsigned short t[64][65];
  int z = blockIdx.z;
  long ib = (long)(z / Hz) * zs_b + (long)(z % Hz) * zs_h;
  long ob = (long)z * zs_out;
  int r0 = blockIdx.y * 64, c0 = blockIdx.x * 64;
  int lane = threadIdx.x & 63, grp = threadIdx.x >> 6;
  for (int i = grp; i < 64; i += 4)
    t[i][lane] = tob(in[ib + (long)(r0 + i) * s_in + c0 + lane]);
  __syncthreads();
  for (int i = grp; i < 64; i += 4)
    out[ob + (long)(c0 + i) * s_out + r0 + lane] = t[lane][i];
}

__global__ void concat_bias(const float* __restrict__ q,
                            const float* __restrict__ k,
                            const float* __restrict__ v,
                            float* __restrict__ o)
{
  int i = blockIdx.x * 256 + threadIdx.x;  // 3072 total
  o[i] = (i < 1024) ? q[i] : (i < 2048) ? k[i - 1024] : v[i - 2048];
}

// ---------------- LayerNorm (optionally fused residual add) ------------
__global__ __launch_bounds__(256) void ln_kernel(
    const float* __restrict__ xin, const unsigned short* __restrict__ addend,
    const float* __restrict__ g, const float* __restrict__ beta,
    unsigned short* __restrict__ yout, float* __restrict__ out1)
{
  int row = blockIdx.x, tid = threadIdx.x;
  size_t base = (size_t)row * E_ + tid * 4;
  float4 xa = *(const float4*)(xin + base);
  float v0 = xa.x, v1 = xa.y, v2 = xa.z, v3 = xa.w;
  if (addend) {
    ushort4 aa = *(const ushort4*)(addend + base);
    v0 += b2f(aa.x); v1 += b2f(aa.y); v2 += b2f(aa.z); v3 += b2f(aa.w);
  }
  if (out1) {
    *(float4*)(out1 + base) = make_float4(v0, v1, v2, v3);
  }
  float s = v0 + v1 + v2 + v3;
  float sq = v0*v0 + v1*v1 + v2*v2 + v3*v3;
  #pragma unroll
  for (int off = 32; off >= 1; off >>= 1) {
    s  += __shfl_xor(s, off);
    sq += __shfl_xor(sq, off);
  }
  __shared__ float red[8];
  int wid = tid >> 6;
  if ((tid & 63) == 0) { red[wid] = s; red[4 + wid] = sq; }
  __syncthreads();
  s  = red[0] + red[1] + red[2] + red[3];
  sq = red[4] + red[5] + red[6] + red[7];
  float mu = s * (1.0f / E_);
  float var = sq * (1.0f / E_) - mu * mu;
  float rs = rsqrtf(var + 1e-5f);
  float4 ga = *(const float4*)(g + tid * 4);
  float4 ba = *(const float4*)(beta + tid * 4);
  ushort4 o;
  o.x = f2b((v0 - mu) * rs * ga.x + ba.x);
  o.y = f2b((v1 - mu) * rs * ga.y + ba.y);
  o.z = f2b((v2 - mu) * rs * ga.z + ba.z);
  o.w = f2b((v3 - mu) * rs * ga.w + ba.w);
  *(ushort4*)(yout + base) = o;
}

// ============ 256x256 BK=64 8-phase bf16 GEMM (m201 port) ==============
// C = A @ Bt^T (+bias)(+relu)(+resid on z==0).  BM=BN=256, BK=64,
// 8 waves (2M x 4N), per-wave 128x64 out (acc[8][4] f32x4 = 128 AGPR).
// LDS 128 KiB: As/Bs[2][256*64], tile t in buf t&1.  Iteration = 2
// K-tiles (e=2i buf0 @P1-P4, o=2i+1 buf1 @P5-P8).  Per phase:
//   {ds_reads || stage 1 half-tile (2 global_load_lds)} -> s_barrier ->
//   lgkmcnt(0)+sched_barrier -> setprio(1) 16 MFMA setprio(0) ->
//   [vmcnt(4) @P4/P8] -> s_barrier.
// Read order per tile: P1 reads ALL B (8 b128, kk0+kk1) + af(mh0,kk0);
// P2/P3/P4 read 4 af each.  So B-buf reads complete at P1, A-buf at P4:
//   stage slots (all WAR-safe by >=1 barrier after last read):
//   P1: buf^1.A-h0 <- tile+1   P2: buf^1.A-h1 <- tile+1
//   P3: buf.B-h0   <- tile+2   P4: buf.B-h1   <- tile+2  + vmcnt(4)
//   P5: buf.A-h0   <- tile+2   P6: buf.A-h1   <- tile+2
//   P7: buf^1.B-h0 <- tile+3   P8: buf^1.B-h1 <- tile+3  + vmcnt(4)
// vmcnt(4) retires exactly the 8 loads of the next-read tile, always
// leaves 4 in flight (counted, never drains -> T4).  Last iter: P4 uses
// vmcnt(0) (tile+2/+3 stages skipped).  Prologue: stage t0 (8 loads) +
// t1.B (4) -> vmcnt(4).
// Frag regs bounded: b0[4]+b1[4] live per tile + af[4] rotating = 48
// VGPR (R1's 2-tile front-load spilled; this cannot).
// LDS geometry/swizzle/XCD map identical to R3 (measured 0 conflicts);
// per-element K-accumulation order unchanged -> bit-identical output.
#define BARC() { asm volatile("" ::: "memory"); __builtin_amdgcn_s_barrier(); asm volatile("" ::: "memory"); }
#define WAITL() { asm volatile("s_waitcnt lgkmcnt(0)" ::: "memory"); __builtin_amdgcn_sched_barrier(0); }

#define MFMA16(mh, BF) do {                                                 \
  __builtin_amdgcn_s_setprio(1);                                            \
  _Pragma("unroll")                                                         \
  for (int mt_ = 0; mt_ < 4; ++mt_)                                         \
    _Pragma("unroll")                                                       \
    for (int nt_ = 0; nt_ < 4; ++nt_)                                       \
      acc[(mh)*4+mt_][nt_] = __builtin_amdgcn_mfma_f32_16x16x32_bf16(       \
          af[mt_], BF[nt_], acc[(mh)*4+mt_][nt_], 0, 0, 0);                 \
  __builtin_amdgcn_s_setprio(0);                                            \
} while (0)

template <typename OutT>
__global__ __launch_bounds__(512, 2) void gemm256(
    const unsigned short* __restrict__ A, const unsigned short* __restrict__ Bt,
    const float* __restrict__ bias, const float* __restrict__ resid,
    OutT* __restrict__ Co, int M, int N, int K, int lda, int ldb,
    int relu, size_t zs)
{
  __shared__ __align__(16) unsigned short As[2][256 * 64];   // 32 KiB each
  __shared__ __align__(16) unsigned short Bs[2][256 * 64];
  int tid = threadIdx.x, lane = tid & 63, wid = tid >> 6;
  int lane15 = lane & 15, quad = lane >> 4;
  int wm = wid >> 2, wn = wid & 3;

  // XCD-chunked block swizzle (M/256 == 32 assumed)
  int i = blockIdx.x;
  int xcd = i & 7, c = i >> 3;
  int bm = xcd * 4 + (c & 3);
  int bn = c >> 2;
  size_t koff = (size_t)blockIdx.z * K;
  int z0 = (blockIdx.z == 0);
  Co += (size_t)blockIdx.z * zs;

  // staging map: thread -> (row sr 0..63 per 64-row chunk, slot sc 0..7)
  // LDS dest linear (tid*16B within chunk); global col pre-swizzled.
  int sr = tid >> 3, sc = tid & 7;
  int gcol = (sc ^ (sr & 7)) * 8;                // ushort col in 64-wide tile
  const unsigned short* Ag = A + koff + (size_t)(bm * 256 + sr) * lda + gcol;
  const unsigned short* Bg = Bt + koff + (size_t)(bn * 256 + sr) * ldb + gcol;
  int dst = tid * 8;                             // ushorts (16B/thread)

  int NT = K >> 6;                               // 64-wide K tiles (even)

  f32x4 acc[8][4];
  #pragma unroll
  for (int m = 0; m < 8; ++m)
    #pragma unroll
    for (int n = 0; n < 4; ++n) acc[m][n] = 0.0f;

  // stage one 128-row half (2 x global_load_lds) of A or B for tile kt
  auto stA = [&](int kt, int h) {
    const unsigned short* s = Ag + (size_t)(h * 128) * lda + kt * 64;
    unsigned short* d = &As[kt & 1][h * 8192] + dst;
    async16(s, d);
    async16(s + (size_t)64 * lda, d + 4096);
  };
  auto stB = [&](int kt, int h) {
    const unsigned short* s = Bg + (size_t)(h * 128) * ldb + kt * 64;
    unsigned short* d = &Bs[kt & 1][h * 8192] + dst;
    async16(s, d);
    async16(s + (size_t)64 * ldb, d + 4096);
  };
  int rsw = lane15 & 7;
  auto ldA = [&](int q, int mh, int m, int kk) {
    return *(const bf16x8*)&As[q][(wm * 128 + mh * 64 + m * 16 + lane15) * 64
                                  + (((kk * 4 + quad) ^ rsw) * 8)];
  };
  auto ldB = [&](int q, int n, int kk) {
    return *(const bf16x8*)&Bs[q][(wn * 64 + n * 16 + lane15) * 64
                                  + (((kk * 4 + quad) ^ rsw) * 8)];
  };

  // prologue: t0 complete (8 loads) + t1.B (4 loads); retire t0, keep t1.B
  stB(0, 0); stB(0, 1); stA(0, 0); stA(0, 1);
  stB(1, 0); stB(1, 1);
  asm volatile("s_waitcnt vmcnt(4)" ::: "memory");
  __builtin_amdgcn_s_barrier();

  #pragma unroll 1
  for (int it = 0; it < (NT >> 1); ++it) {
    int u = 2 * it;
    bool more = (u + 2 < NT);
    bf16x8 af[4], b0[4], b1[4];

    // ================= tile u (buf0) =================
    // P1: all B + af(mh0,kk0); stage buf1.A-h0 <- u+1
    #pragma unroll
    for (int n = 0; n < 4; ++n) b0[n] = ldB(0, n, 0);
    #pragma unroll
    for (int n = 0; n < 4; ++n) b1[n] = ldB(0, n, 1);
    #pragma unroll
    for (int m = 0; m < 4; ++m) af[m] = ldA(0, 0, m, 0);
    stA(u + 1, 0);
    BARC(); WAITL();
    MFMA16(0, b0);
    BARC();
    // P2: af(mh1,kk0); stage buf1.A-h1 <- u+1
    #pragma unroll
    for (int m = 0; m < 4; ++m) af[m] = ldA(0, 1, m, 0);
    stA(u + 1, 1);
    BARC(); WAITL();
    MFMA16(1, b0);
    BARC();
    // P3: af(mh0,kk1); stage buf0.B-h0 <- u+2 (B reads of u done @P1)
    #pragma unroll
    for (int m = 0; m < 4; ++m) af[m] = ldA(0, 0, m, 1);
    if (more) stB(u + 2, 0);
    BARC(); WAITL();
    MFMA16(0, b1);
    BARC();
    // P4: af(mh1,kk1); stage buf0.B-h1 <- u+2; retire tile u+1's 8 loads
    #pragma unroll
    for (int m = 0; m < 4; ++m) af[m] = ldA(0, 1, m, 1);
    if (more) stB(u + 2, 1);
    BARC(); WAITL();
    MFMA16(1, b1);
    if (more) { asm volatile("s_waitcnt vmcnt(4)" ::: "memory"); }
    else      { asm volatile("s_waitcnt vmcnt(0)" ::: "memory"); }
    BARC();

    // ================= tile u+1 (buf1) =================
    // P5: all B + af(mh0,kk0); stage buf0.A-h0 <- u+2 (A reads of u done @P4)
    #pragma unroll
    for (int n = 0; n < 4; ++n) b0[n] = ldB(1, n, 0);
    #pragma unroll
    for (int n = 0; n < 4; ++n) b1[n] = ldB(1, n, 1);
    #pragma unroll
    for (int m = 0; m < 4; ++m) af[m] = ldA(1, 0, m, 0);
    if (more) stA(u + 2, 0);
    BARC(); WAITL();
    MFMA16(0, b0);
    BARC();
    // P6: af(mh1,kk0); stage buf0.A-h1 <- u+2
    #pragma unroll
    for (int m = 0; m < 4; ++m) af[m] = ldA(1, 1, m, 0);
    if (more) stA(u + 2, 1);
    BARC(); WAITL();
    MFMA16(1, b0);
    BARC();
    // P7: af(mh0,kk1); stage buf1.B-h0 <- u+3 (B reads of u+1 done @P5)
    #pragma unroll
    for (int m = 0; m < 4; ++m) af[m] = ldA(1, 0, m, 1);
    if (more) stB(u + 3, 0);
    BARC(); WAITL();
    MFMA16(0, b1);
    BARC();
    // P8: af(mh1,kk1); stage buf1.B-h1 <- u+3; retire tile u+2's 8 loads
    #pragma unroll
    for (int m = 0; m < 4; ++m) af[m] = ldA(1, 1, m, 1);
    if (more) stB(u + 3, 1);
    BARC(); WAITL();
    MFMA16(1, b1);
    if (more) { asm volatile("s_waitcnt vmcnt(4)" ::: "memory"); }
    BARC();
  }

  #pragma unroll
  for (int nt = 0; nt < 4; ++nt) {
    int col = bn * 256 + wn * 64 + nt * 16 + lane15;
    float bv = (bias && z0) ? bias[col] : 0.0f;
    #pragma unroll
    for (int mt = 0; mt < 8; ++mt) {
      int row0 = bm * 256 + wm * 128 + mt * 16 + quad * 4;
      #pragma unroll
      for (int r = 0; r < 4; ++r) {
        float val = acc[mt][nt][r] + bv;
        if (relu) val = fmaxf(val, 0.0f);
        if (resid && z0) val += resid[(size_t)(row0 + r) * N + col];
        store_out(&Co[(size_t)(row0 + r) * N + col], val);
      }
    }
  }
}

// ---- split-K combine: out = p0 + p1 (bias/resid folded into z=0) ------
__global__ __launch_bounds__(256) void add2(
    const float* __restrict__ p0, const float* __restrict__ p1,
    float* __restrict__ out)
{
  size_t i = ((size_t)blockIdx.x * 256 + threadIdx.x) * 4;
  float4 a = *(const float4*)(p0 + i);
  float4 b = *(const float4*)(p1 + i);
  *(float4*)(out + i) = make_float4(a.x + b.x, a.y + b.y, a.z + b.z, a.w + b.w);
}

// -------- MFMA flash attention v5 (v3 + causal key-range split) --------
// Block = 128 Q rows of one head (8 waves x 16 rows, 512 threads).
// No-max softmax in log2 domain -> partials over disjoint key ranges
// combine exactly by addition.  qblk >= 8 is split into two key-range
// halves (each <= 16 tiles, balancing the causal load); partial O (fp32)
// and l go to scratch, combined by attn_combine.
// blockIdx.x decode: bx<16 -> qblk=15-(bx>>1), half p=bx&1 (split);
//                    bx>=16 -> qblk=23-bx (unsplit).
__global__ __launch_bounds__(512) void attn_kernel(
    const unsigned short* __restrict__ qkv, const unsigned short* __restrict__ vt,
    unsigned short* __restrict__ attnb,
    float* __restrict__ opart0, float* __restrict__ opart1,
    float* __restrict__ lpart)
{
  __shared__ __align__(16) unsigned short Klds[64 * 64];   // [key][d]
  __shared__ __align__(16) unsigned short Vlds[64 * 64];   // [d][key]
  __shared__ __align__(16) unsigned short Plds[8][16 * 72];
  int tid = threadIdx.x, lane = tid & 63, widx = tid >> 6;
  int lane15 = lane & 15, quad = lane >> 4;

  int bx = blockIdx.x;
  int qblk, p, split;
  if (bx < 16) { qblk = 15 - (bx >> 1); p = bx & 1; split = 1; }
  else         { qblk = 23 - bx;        p = 0;      split = 0; }
  int ntiles = 2 * qblk + 2;
  int kt0 = (split && p) ? (qblk + 1) : 0;
  int kt1 = (split && !p) ? (qblk + 1) : ntiles;

  int bh = blockIdx.y;                   // 0..63
  int b = bh >> 4, h = bh & 15;
  int q0w = qblk * 128 + widx * 16;      // this wave's first Q row

  const float QSCALE = 0.18033688011112042f;  // 0.125 / ln(2)
  const unsigned short* qb = qkv + (size_t)(b * C_ + q0w + lane15) * 3072 + h * 64;
  bf16x8 qa0 = *(const bf16x8*)(qb + quad * 8);
  bf16x8 qa1 = *(const bf16x8*)(qb + 32 + quad * 8);
  #pragma unroll
  for (int j = 0; j < 8; ++j) {
    qa0[j] = (__bf16)((float)qa0[j] * QSCALE);
    qa1[j] = (__bf16)((float)qa1[j] * QSCALE);
  }

  float lsum[4];
  f32x4 o[4];
  #pragma unroll
  for (int r = 0; r < 4; ++r) lsum[r] = 0.0f;
  #pragma unroll
  for (int nt = 0; nt < 4; ++nt) o[nt] = 0.0f;

  int sr = tid >> 3, sc = tid & 7, sw = sr & 7;
  const unsigned short* kg = qkv + (size_t)(b * C_ + kt0 * 64 + sr) * 3072 + 1024 + h * 64 + (sc ^ sw) * 8;
  const unsigned short* vg = vt + (size_t)bh * 64 * 2048 + (size_t)sr * 2048 + (sc ^ sw) * 8 + kt0 * 64;
  unsigned short* kl = &Klds[sr * 64 + sc * 8];
  unsigned short* vl = &Vlds[sr * 64 + sc * 8];
  int swr = lane15 & 7;

  for (int kt = kt0; kt < kt1; ++kt) {
    int k0 = kt * 64;
    async16(kg, kl);
    async16(vg, vl);
    kg += (size_t)64 * 3072;
    vg += 64;
    __syncthreads();

    if (k0 <= q0w + 15) {
      f32x4 s[4];
      #pragma unroll
      for (int g = 0; g < 4; ++g) s[g] = 0.0f;
      #pragma unroll
      for (int g = 0; g < 4; ++g) {
        int row = g * 16 + lane15;
        bf16x8 kf0 = *(const bf16x8*)&Klds[row * 64 + ((quad ^ swr) * 8)];
        bf16x8 kf1 = *(const bf16x8*)&Klds[row * 64 + (((4 + quad) ^ swr) * 8)];
        s[g] = __builtin_amdgcn_mfma_f32_16x16x32_bf16(qa0, kf0, s[g], 0, 0, 0);
        s[g] = __builtin_amdgcn_mfma_f32_16x16x32_bf16(qa1, kf1, s[g], 0, 0, 0);
      }

      if (k0 + 63 > q0w) {
        #pragma unroll
        for (int g = 0; g < 4; ++g)
          #pragma unroll
          for (int r = 0; r < 4; ++r)
            if (k0 + g * 16 + lane15 > q0w + quad * 4 + r) s[g][r] = -3.0e38f;
      }

      float pv[4][4];
      #pragma unroll
      for (int g = 0; g < 4; ++g)
        #pragma unroll
        for (int r = 0; r < 4; ++r) pv[g][r] = exp2f(s[g][r]);
      #pragma unroll
      for (int r = 0; r < 4; ++r)
        lsum[r] += (pv[0][r] + pv[1][r]) + (pv[2][r] + pv[3][r]);

      __bf16* prow = (__bf16*)&Plds[widx][0];
      #pragma unroll
      for (int g = 0; g < 4; ++g)
        #pragma unroll
        for (int r = 0; r < 4; ++r)
          prow[(quad * 4 + r) * 72 + g * 16 + lane15] = (__bf16)pv[g][r];
      asm volatile("s_waitcnt lgkmcnt(0)" ::: "memory");
      bf16x8 pa0 = *(const bf16x8*)&Plds[widx][lane15 * 72 + quad * 8];
      bf16x8 pa1 = *(const bf16x8*)&Plds[widx][lane15 * 72 + 32 + quad * 8];

      #pragma unroll
      for (int nt = 0; nt < 4; ++nt) {
        int d = nt * 16 + lane15;
        bf16x8 vf0 = *(const bf16x8*)&Vlds[d * 64 + ((quad ^ swr) * 8)];
        bf16x8 vf1 = *(const bf16x8*)&Vlds[d * 64 + (((4 + quad) ^ swr) * 8)];
        o[nt] = __builtin_amdgcn_mfma_f32_16x16x32_bf16(pa0, vf0, o[nt], 0, 0, 0);
        o[nt] = __builtin_amdgcn_mfma_f32_16x16x32_bf16(pa1, vf1, o[nt], 0, 0, 0);
      }
    }
    __syncthreads();
  }

  #pragma unroll
  for (int off = 1; off <= 8; off <<= 1)
    #pragma unroll
    for (int r = 0; r < 4; ++r)
      lsum[r] += __shfl_xor(lsum[r], off);

  if (!split) {
    float rl[4];
    #pragma unroll
    for (int r = 0; r < 4; ++r) rl[r] = 1.0f / lsum[r];
    #pragma unroll
    for (int nt = 0; nt < 4; ++nt)
      #pragma unroll
      for (int r = 0; r < 4; ++r) {
        float val = o[nt][r] * rl[r];
        attnb[(size_t)(b * C_ + q0w + quad * 4 + r) * E_ + h * 64 + nt * 16 + lane15] = f2b(val);
      }
  } else {
    float* op = p ? opart1 : opart0;
    size_t rbase = (size_t)bh * 1024 + (q0w - 1024) + quad * 4;
    #pragma unroll
    for (int nt = 0; nt < 4; ++nt)
      #pragma unroll
      for (int r = 0; r < 4; ++r)
        op[(rbase + r) * 64 + nt * 16 + lane15] = o[nt][r];
    if (lane15 == 0) {
      float* lp = lpart + (size_t)p * 65536;
      #pragma unroll
      for (int r = 0; r < 4; ++r) lp[rbase + r] = lsum[r];
    }
  }
}

// combine split-attention partials: attnb = (O0+O1)/(l0+l1) for rows 1024+
__global__ __launch_bounds__(256) void attn_combine(
    const float* __restrict__ opart0, const float* __restrict__ opart1,
    const float* __restrict__ lpart, unsigned short* __restrict__ attnb)
{
  size_t i = (size_t)blockIdx.x * 256 + threadIdx.x;  // over 64*1024*64
  int d = (int)(i & 63);
  size_t rowi = i >> 6;                 // bh*1024 + row
  int bh = (int)(rowi >> 10), row = (int)(rowi & 1023);
  float ov = opart0[rowi * 64 + d] + opart1[rowi * 64 + d];
  float lv = lpart[rowi] + lpart[65536 + rowi];
  int b = bh >> 4, h = bh & 15;
  attnb[(size_t)(b * C_ + 1024 + row) * E_ + h * 64 + d] = f2b(ov / lv);
}

// ---------------------------- launcher ---------------------------------
extern "C" void kernel_launch(void* const* d_in, const int* in_sizes, int n_in,
                              void* d_out, int out_size, void* d_ws, size_t ws_size,
                              hipStream_t stream)
{
  const float* x   = (const float*)d_in[0];
  const float* Wq  = (const float*)d_in[1];
  const float* bq  = (const float*)d_in[2];
  const float* Wk  = (const float*)d_in[3];
  const float* bk  = (const float*)d_in[4];
  const float* Wv  = (const float*)d_in[5];
  const float* bv  = (const float*)d_in[6];
  const float* g1  = (const float*)d_in[7];
  const float* be1 = (const float*)d_in[8];
  const float* g2  = (const float*)d_in[9];
  const float* be2 = (const float*)d_in[10];
  const float* W1  = (const float*)d_in[11];
  const float* bm1 = (const float*)d_in[12];
  const float* W2  = (const float*)d_in[13];
  const float* bm2 = (const float*)d_in[14];

  char* ws = (char*)d_ws;
  // Region lifetime plan:
  //  [0,16M)      norm1 (LN1 out, dead after QKV gemm) -> lpart during attn
  //               -> norm2 (LN2 out) -> overlaid by part0 at MLP2
  //  [123.7M,+32M) free during attn -> opart1 -> out1 (LN2) 
  //  [165.7M,+32M) free during attn -> opart0 -> part1 (MLP2 z1)
  float*          part0 = (float*)(ws + 0);                   // 32 MB fp32 [8192][1024]
  unsigned short* norm1 = (unsigned short*)(ws + 0);          // 16 MB bf16 (reused as norm2)
  unsigned short* wT    = (unsigned short*)(ws + 16777216);   // 6 MB  bf16 WqkvT [3072][1024]
  unsigned short* w1T   = (unsigned short*)(ws + 23068672);   // 8 MB  bf16 [4096][1024]
  float*          biasq = (float*)(ws + 39845888);            // 12 KB fp32 [3072]
  unsigned short* qkv   = (unsigned short*)(ws + 39858176);   // 48 MB bf16 [8192][3072]
  unsigned short* vtb   = (unsigned short*)(ws + 90189824);   // 16 MB bf16 [64][64][2048]
  unsigned short* mid   = (unsigned short*)(ws + 39858176);   // 64 MB bf16 [8192][4096] (aliases qkv+vtb)
  unsigned short* attnb = (unsigned short*)(ws + 106967040);  // 16 MB bf16 [8192][1024]
  float*          out1  = (float*)(ws + 123744256);           // 32 MB fp32 [8192][1024]
  unsigned short* w2T   = (unsigned short*)(ws + 157298688);  // 8 MB  bf16 [1024][4096]
  float*          part1 = (float*)(ws + 165687296);           // 32 MB fp32 [8192][1024]
  // attn split partials (dead-region overlays, see plan above):
  float*          opart0 = (float*)(ws + 165687296);          // 16.78 MB
  float*          opart1 = (float*)(ws + 123744256);          // 16.78 MB
  float*          lpartb = (float*)(ws + 0);                  // 0.5 MB
  // total: 199,241,728 bytes
  size_t part_zs = ((size_t)165687296) / 4;                   // part1 - part0 in floats

  // weight transposes (+fp32->bf16 convert) -> [N][K]
  transpose64<float><<<dim3(16, 16, 1), 256, 0, stream>>>(Wq, wT,               1024, 1024, 1, 0, 0, 0);
  transpose64<float><<<dim3(16, 16, 1), 256, 0, stream>>>(Wk, wT + 1024 * 1024, 1024, 1024, 1, 0, 0, 0);
  transpose64<float><<<dim3(16, 16, 1), 256, 0, stream>>>(Wv, wT + 2048 * 1024, 1024, 1024, 1, 0, 0, 0);
  transpose64<float><<<dim3(64, 16, 1), 256, 0, stream>>>(W1, w1T, 4096, 1024, 1, 0, 0, 0);
  transpose64<float><<<dim3(16, 64, 1), 256, 0, stream>>>(W2, w2T, 1024, 4096, 1, 0, 0, 0);
  concat_bias<<<12, 256, 0, stream>>>(bq, bk, bv, biasq);

  // LN1: norm1 = LN(x) in bf16
  ln_kernel<<<ROWS_, 256, 0, stream>>>(x, nullptr, g1, be1, norm1, nullptr);

  // fused QKV GEMM: [8192][1024] @ [3072][1024]^T -> [8192][3072] bf16
  // grid = 32 M-blocks x 12 N-blocks = 384
  gemm256<unsigned short><<<dim3(384, 1, 1), 512, 0, stream>>>(
      norm1, wT, biasq, nullptr, qkv, 8192, 3072, 1024, 1024, 1024, 0, 0);

  // V^T per head: vt[b*H+h][d][c]
  transpose64<unsigned short><<<dim3(1, 32, 64), 256, 0, stream>>>(
      qkv + 2048, vtb, 3072, 2048, 16, (long)C_ * 3072, 64, (long)64 * 2048);

  // causal flash attention v5 (split heavy qblks)
  attn_kernel<<<dim3(24, 64), 512, 0, stream>>>(qkv, vtb, attnb, opart0, opart1, lpartb);
  attn_combine<<<16384, 256, 0, stream>>>(opart0, opart1, lpartb, attnb);

  // out1 = x + attn (fp32) ; norm2 = LN(out1) bf16
  ln_kernel<<<ROWS_, 256, 0, stream>>>(x, attnb, g2, be2, norm1, out1);

  // MLP1: relu(norm2 @ W1^T + bm1) -> mid bf16  (grid 32x16 = 512)
  gemm256<unsigned short><<<dim3(512, 1, 1), 512, 0, stream>>>(
      norm1, w1T, bm1, nullptr, mid, 8192, 4096, 1024, 1024, 1024, 1, 0);

  // MLP2 split-K: z=0 adds bm2+out1, z=1 raw partial (grid 32x4 x2)
  gemm256<float><<<dim3(128, 1, 2), 512, 0, stream>>>(
      mid, w2T, bm2, out1, part0, 8192, 1024, 2048, 4096, 4096, 0, part_zs);
  // out = part0 + part1
  add2<<<8192, 256, 0, stream>>>(part0, part1, (float*)d_out);
}